// Round 3
// baseline (540.773 us; speedup 1.0000x reference)
//
#include <hip/hip_runtime.h>
#include <hip/hip_bf16.h>
#include <math.h>

// Problem constants
#define BB 64
#define SS 2048
#define IN_ 256
#define MSLOT 8
#define HH 8
#define HD_ 64
#define MM 512
#define NG_ 1024

typedef __attribute__((ext_vector_type(8))) short short8;
typedef __attribute__((ext_vector_type(8))) unsigned short ushort8;
typedef __attribute__((ext_vector_type(4))) float f32x4;

__device__ __forceinline__ unsigned short f2bf(float f) {
    unsigned int u = __builtin_bit_cast(unsigned int, f);
    u += 0x7fff + ((u >> 16) & 1);   // round-to-nearest-even
    return (unsigned short)(u >> 16);
}

__device__ __forceinline__ float block_sum256(float v, float* red) {
    int t = threadIdx.x;
    red[t] = v; __syncthreads();
    for (int s = 128; s > 0; s >>= 1) {
        if (t < s) red[t] += red[t + s];
        __syncthreads();
    }
    float r = red[0];
    __syncthreads();
    return r;
}

__device__ __forceinline__ float2 block_sum512_2(float a, float b, float* rA, float* rB) {
    int t = threadIdx.x;
    rA[t] = a; rB[t] = b; __syncthreads();
    for (int s = 256; s > 0; s >>= 1) {
        if (t < s) { rA[t] += rA[t + s]; rB[t] += rB[t + s]; }
        __syncthreads();
    }
    float2 r = make_float2(rA[0], rB[0]);
    __syncthreads();
    return r;
}

// ---- LDS tile staging helpers: 64 rows x 256 cols bf16, 16B-chunk XOR swizzle
__device__ __forceinline__ void stage_tile_bf16(unsigned short* lds,
                                                const unsigned short* __restrict__ src,
                                                int t) {
#pragma unroll
    for (int it = 0; it < 8; ++it) {
        int c = t + it * 256;
        int r = c >> 5, ch = c & 31;
        ushort8 v = *(const ushort8*)(src + (size_t)r * 256 + ch * 8);
        int sch = ch ^ (r & 7);
        *(ushort8*)(lds + r * 256 + sch * 8) = v;
    }
}

__device__ __forceinline__ void stage_tile_f32cvt(unsigned short* lds,
                                                  const float* __restrict__ src,
                                                  int t) {
#pragma unroll
    for (int it = 0; it < 8; ++it) {
        int c = t + it * 256;
        int r = c >> 5, ch = c & 31;
        const float* p = src + (size_t)r * 256 + ch * 8;
        float4 f0 = *(const float4*)p;
        float4 f1 = *(const float4*)(p + 4);
        ushort8 v;
        v[0] = f2bf(f0.x); v[1] = f2bf(f0.y); v[2] = f2bf(f0.z); v[3] = f2bf(f0.w);
        v[4] = f2bf(f1.x); v[5] = f2bf(f1.y); v[6] = f2bf(f1.z); v[7] = f2bf(f1.w);
        int sch = ch ^ (r & 7);
        *(ushort8*)(lds + r * 256 + sch * 8) = v;
    }
}

__device__ __forceinline__ short8 frag_ld(const unsigned short* lds, int row, int chunk) {
    int sch = chunk ^ (row & 7);
    return *(const short8*)(lds + row * 256 + sch * 8);
}

// ---------------- K1a: fused weights. WikT[o][i]=sum_j Wi[i][j]Wk[j][o]; Wiv[i][o]=sum_j Wi[i][j]Wv[j][o]
__global__ __launch_bounds__(256) void k_fuse_w(const float* __restrict__ Wi,
                                                const float* __restrict__ Wk,
                                                const float* __restrict__ Wv,
                                                const float* __restrict__ bi,
                                                const float* __restrict__ bk,
                                                const float* __restrict__ bv,
                                                float* __restrict__ WikT,
                                                float* __restrict__ Wiv,
                                                float* __restrict__ bkf,
                                                float* __restrict__ bvf) {
    int blk = blockIdx.x;          // 0..1023
    int which = blk >> 9;          // 0: k, 1: v
    int o = blk & 511;
    const float* W = which ? Wv : Wk;
    const float* bx = which ? bv : bk;
    float* bf = which ? bvf : bkf;

    __shared__ float col[512];
    __shared__ float red[256];
    int t = threadIdx.x;
    col[t]       = W[t * 512 + o];
    col[t + 256] = W[(t + 256) * 512 + o];
    __syncthreads();

    const float* wi_row = Wi + t * 512;   // t = i (0..255)
    float acc = 0.f;
    for (int j = 0; j < 512; ++j) acc += wi_row[j] * col[j];
    if (which) Wiv[t * 512 + o] = acc;      // i-major
    else       WikT[o * 256 + t] = acc;     // o-major

    float p = bi[t] * col[t] + bi[t + 256] * col[t + 256];
    float s = block_sum256(p, red);
    if (t == 0) bf[o] = s + bx[o];
}

// ---------------- K1b: q[b,ms,o] = memory[b,ms,:]@Wq + bq
__global__ __launch_bounds__(256) void k_q(const float* __restrict__ memory,
                                           const float* __restrict__ Wq,
                                           const float* __restrict__ bq,
                                           float* __restrict__ q) {
    int bms = blockIdx.x;
    __shared__ float row[512];
    int t = threadIdx.x;
    row[t]       = memory[bms * 512 + t];
    row[t + 256] = memory[bms * 512 + t + 256];
    __syncthreads();
    for (int oo = 0; oo < 2; ++oo) {
        int o = oo * 256 + t;
        float acc = bq[o];
        for (int j = 0; j < 512; ++j) acc += row[j] * Wq[j * 512 + o];
        q[bms * 512 + o] = acc;
    }
}

// ---------------- K1c: P[b,hm,i] (bf16); c[b,hm]=sum_d q*bkf
__global__ __launch_bounds__(256) void k_p(const float* __restrict__ q,
                                           const float* __restrict__ WikT,
                                           const float* __restrict__ bkf,
                                           unsigned short* __restrict__ Pb,
                                           float* __restrict__ cbuf) {
    int blk = blockIdx.x;           // b*64 + hm, hm = h*8+ms
    int b = blk >> 6, hm = blk & 63;
    int h = hm >> 3, ms = hm & 7;
    int t = threadIdx.x;
    __shared__ float qv[64];
    __shared__ float red[64];
    if (t < 64) qv[t] = q[(b * 8 + ms) * 512 + h * 64 + t];
    __syncthreads();
    float acc = 0.f;
    for (int d = 0; d < 64; ++d) acc += qv[d] * WikT[(h * 64 + d) * 256 + t];
    Pb[blk * 256 + t] = f2bf(acc);
    if (t < 64) red[t] = qv[t] * bkf[h * 64 + t];
    __syncthreads();
    for (int s = 32; s > 0; s >>= 1) {
        if (t < s) red[t] += red[t + s];
        __syncthreads();
    }
    if (t == 0) cbuf[blk] = red[0];
}

// ---------------- Wi^T -> bf16
__global__ __launch_bounds__(256) void k_wiT(const float* __restrict__ Wi,
                                             unsigned short* __restrict__ WiTb) {
    int d = blockIdx.x;      // 0..511
    int k = threadIdx.x;     // 0..255
    WiTb[d * 256 + k] = f2bf(Wi[k * 512 + d]);
}

// ---------------- K2 (MFMA): scores[b,hm,s] = P[b,hm,:]·inputs[b,s,:] + c[b,hm]
__global__ __launch_bounds__(256) void k_scores_mfma(const float* __restrict__ inputs,
                                                     const unsigned short* __restrict__ Pb,
                                                     const float* __restrict__ cbuf,
                                                     float* __restrict__ scores) {
    __shared__ unsigned short Pl[64 * 256];
    __shared__ unsigned short Il[64 * 256];
    int t = threadIdx.x;
    int stile = blockIdx.x;   // 0..31 (64 s each)
    int b = blockIdx.y;

    stage_tile_bf16(Pl, Pb + (size_t)b * 64 * 256, t);
    const float* src = inputs + ((size_t)b * SS + stile * 64) * IN_;
    stage_tile_f32cvt(Il, src, t);
    __syncthreads();

    int l = t & 63, w = t >> 6;
    int kg = l >> 4, r16 = l & 15;
    short8 a[8];
#pragma unroll
    for (int kk = 0; kk < 8; ++kk) a[kk] = frag_ld(Pl, w * 16 + r16, kk * 4 + kg);

#pragma unroll
    for (int nt = 0; nt < 4; ++nt) {
        f32x4 acc = {0.f, 0.f, 0.f, 0.f};
#pragma unroll
        for (int kk = 0; kk < 8; ++kk) {
            short8 bf = frag_ld(Il, nt * 16 + r16, kk * 4 + kg);
            acc = __builtin_amdgcn_mfma_f32_16x16x32_bf16(a[kk], bf, acc, 0, 0, 0);
        }
        int s = stile * 64 + nt * 16 + r16;
#pragma unroll
        for (int j = 0; j < 4; ++j) {
            int hm = w * 16 + kg * 4 + j;
            scores[((size_t)(b * 64 + hm)) * SS + s] = acc[j] + cbuf[b * 64 + hm];
        }
    }
}

// ---------------- K3: per-row softmax + top-3
__global__ __launch_bounds__(256) void k_topk(const float* __restrict__ scores,
                                              float* __restrict__ topk_p,
                                              int* __restrict__ topk_idx) {
    int row = blockIdx.x;   // b*64 + hm
    const float* sr = scores + (size_t)row * SS;
    int t = threadIdx.x;
    float v[8];
#pragma unroll
    for (int k = 0; k < 8; ++k) v[k] = sr[k * 256 + t];

    __shared__ float red[256];
    __shared__ float vred[256];
    __shared__ int ired[256];

    float m = -INFINITY;
#pragma unroll
    for (int k = 0; k < 8; ++k) m = fmaxf(m, v[k]);
    red[t] = m; __syncthreads();
    for (int s = 128; s > 0; s >>= 1) {
        if (t < s) red[t] = fmaxf(red[t], red[t + s]);
        __syncthreads();
    }
    float rowmax = red[0]; __syncthreads();

    float sum = 0.f;
#pragma unroll
    for (int k = 0; k < 8; ++k) sum += expf(v[k] - rowmax);
    float rowsum = block_sum256(sum, red);

    int found[3]; float fval[3];
    for (int r = 0; r < 3; ++r) {
        float bv = -INFINITY; int bidx = 0x7fffffff;
#pragma unroll
        for (int k = 0; k < 8; ++k) {
            int gi = k * 256 + t;
            bool skip = false;
            for (int j = 0; j < r; ++j) skip = skip || (found[j] == gi);
            float val = skip ? -INFINITY : v[k];
            if (val > bv || (val == bv && gi < bidx)) { bv = val; bidx = gi; }
        }
        vred[t] = bv; ired[t] = bidx; __syncthreads();
        for (int s = 128; s > 0; s >>= 1) {
            if (t < s) {
                float ov = vred[t + s]; int oi = ired[t + s];
                if (ov > vred[t] || (ov == vred[t] && oi < ired[t])) { vred[t] = ov; ired[t] = oi; }
            }
            __syncthreads();
        }
        found[r] = ired[0];
        fval[r] = vred[0];
        __syncthreads();
    }
    if (t == 0) {
#pragma unroll
        for (int r = 0; r < 3; ++r) {
            topk_idx[row * 3 + r] = found[r];
            topk_p[row * 3 + r] = expf(fval[r] - rowmax) / rowsum;
        }
    }
}

// ---------------- K4: gather + att + LN1 fused.
// att[b,ms,o] = (sum_j p_j inputs[b,s_j,:])·Wiv[:,o] + (sum_j p_j)·bvf[o]; mem1 = LN(memory+att)
__global__ __launch_bounds__(256) void k_att2(const float* __restrict__ inputs,
                                              const float* __restrict__ Wiv,
                                              const float* __restrict__ bvf,
                                              const float* __restrict__ topk_p,
                                              const int* __restrict__ topk_idx,
                                              const float* __restrict__ memory,
                                              const float* __restrict__ g1,
                                              const float* __restrict__ b1,
                                              float* __restrict__ mem1) {
    int bms = blockIdx.x;           // b*8 + ms
    int b = bms >> 3, ms = bms & 7;
    int t = threadIdx.x;
    __shared__ float w[8 * 256];
    __shared__ float ps[8];
    __shared__ float red[256];

#pragma unroll
    for (int h = 0; h < 8; ++h) {
        int row = (b * 64 + h * 8 + ms) * 3;
        float acc = 0.f, psum = 0.f;
#pragma unroll
        for (int j = 0; j < 3; ++j) {
            int sj = topk_idx[row + j];
            float pj = topk_p[row + j];
            acc += pj * inputs[((size_t)b * SS + sj) * IN_ + t];
            psum += pj;
        }
        w[h * 256 + t] = acc;
        if (t == 0) ps[h] = psum;
    }
    __syncthreads();

    float a_val[2];
#pragma unroll
    for (int oo = 0; oo < 2; ++oo) {
        int o = oo * 256 + t;
        int h = o >> 6;
        float acc = ps[h] * bvf[o];
        const float* wh = w + h * 256;
#pragma unroll 8
        for (int i = 0; i < 256; ++i) acc += wh[i] * Wiv[i * 512 + o];
        a_val[oo] = acc;
    }

    // LN1 on memory + att
    float m0 = memory[bms * 512 + t], m1 = memory[bms * 512 + t + 256];
    float x0 = m0 + a_val[0], x1 = m1 + a_val[1];
    float mu = block_sum256(x0 + x1, red) * (1.f / 512.f);
    float d0 = x0 - mu, d1 = x1 - mu;
    float var = block_sum256(d0 * d0 + d1 * d1, red) * (1.f / 512.f);
    float rstd = rsqrtf(var + 1e-5f);
    mem1[bms * 512 + t]       = d0 * rstd * g1[t] + b1[t];
    mem1[bms * 512 + t + 256] = d1 * rstd * g1[t + 256] + b1[t + 256];
}

// ---------------- K5 (MFMA): giacc[b,d] += sum_s relu(rw[d]*(inputs[b,s,:]@Wi[:,d] + bi[d]))
__global__ __launch_bounds__(256) void k_gimean_mfma(const float* __restrict__ inputs,
                                                     const unsigned short* __restrict__ WiTb,
                                                     const float* __restrict__ bi,
                                                     const float* __restrict__ rw,
                                                     float* __restrict__ giacc) {
    __shared__ unsigned short Al[64 * 256];
    __shared__ unsigned short Bl[64 * 256];
    __shared__ float gl[512];
    int t = threadIdx.x;
    int stile = blockIdx.x;   // 0..31
    int b = blockIdx.y;
    gl[t] = 0.f; gl[t + 256] = 0.f;

    const float* src = inputs + ((size_t)b * SS + stile * 64) * IN_;
    stage_tile_f32cvt(Al, src, t);
    __syncthreads();

    int l = t & 63, w = t >> 6;
    int kg = l >> 4, r16 = l & 15;
    short8 a[8];
#pragma unroll
    for (int kk = 0; kk < 8; ++kk) a[kk] = frag_ld(Al, w * 16 + r16, kk * 4 + kg);

    for (int dt = 0; dt < 8; ++dt) {
        __syncthreads();
        stage_tile_bf16(Bl, WiTb + (size_t)dt * 64 * 256, t);
        __syncthreads();
#pragma unroll
        for (int nt = 0; nt < 4; ++nt) {
            f32x4 acc = {0.f, 0.f, 0.f, 0.f};
#pragma unroll
            for (int kk = 0; kk < 8; ++kk) {
                short8 bf = frag_ld(Bl, nt * 16 + r16, kk * 4 + kg);
                acc = __builtin_amdgcn_mfma_f32_16x16x32_bf16(a[kk], bf, acc, 0, 0, 0);
            }
            int d = dt * 64 + nt * 16 + r16;
            float bid = bi[d], rwd = rw[d];
            float v = 0.f;
#pragma unroll
            for (int j = 0; j < 4; ++j) v += fmaxf(rwd * (acc[j] + bid), 0.f);
            v += __shfl_xor(v, 16);
            v += __shfl_xor(v, 32);
            if (kg == 0) atomicAdd(&gl[d], v);
        }
    }
    __syncthreads();
    atomicAdd(&giacc[b * 512 + t], gl[t]);
    atomicAdd(&giacc[b * 512 + 256 + t], gl[t + 256]);
}

// ---------------- K6a: gate_in[b,o] = (gi_acc[b,:]/S)@Wr + br   (256 blocks)
__global__ __launch_bounds__(256) void k_gatein2(const float* __restrict__ gi_acc,
                                                 const float* __restrict__ Wr,
                                                 const float* __restrict__ br,
                                                 float* __restrict__ gate_in) {
    int b = blockIdx.x >> 2, ot = blockIdx.x & 3;
    int t = threadIdx.x;
    int o = ot * 256 + t;
    __shared__ float gm[512];
    gm[t]       = gi_acc[b * 512 + t] * (1.0f / 2048.0f);
    gm[t + 256] = gi_acc[b * 512 + t + 256] * (1.0f / 2048.0f);
    __syncthreads();
    float acc = br[o];
#pragma unroll 8
    for (int d = 0; d < 512; ++d) acc += gm[d] * Wr[d * 1024 + o];
    gate_in[b * 1024 + o] = acc;
}

// ---------------- K6b: sig_gates[b,ms,o] = sigmoid(tanh(memory[b,ms,:])@Wg[ms,:,o] + gate_in[b,o] + bias)
__global__ __launch_bounds__(256) void k_gates(const float* __restrict__ memory,
                                               const float* __restrict__ Wg,
                                               const float* __restrict__ gate_in,
                                               const float* __restrict__ fb,
                                               const float* __restrict__ ib,
                                               float* __restrict__ sg) {
    int ms = blockIdx.x & 7;
    int ot = blockIdx.x >> 3;        // 0..31, 32 o each
    int obase = ot * 32;
    int t = threadIdx.x;
    int o_l = t & 31, bq = t >> 5;   // bq 0..7

    __shared__ float A_l[64 * 128];  // 32 KB
    float acc[8];
#pragma unroll
    for (int j = 0; j < 8; ++j) acc[j] = 0.f;

    for (int kc = 0; kc < 4; ++kc) {
        __syncthreads();
#pragma unroll
        for (int it = 0; it < 32; ++it) {
            int idx = t + it * 256;
            int bb = idx >> 7, dl = idx & 127;
            A_l[idx] = tanhf(memory[(bb * 8 + ms) * 512 + kc * 128 + dl]);
        }
        __syncthreads();
#pragma unroll 4
        for (int dl = 0; dl < 128; ++dl) {
            float wv = Wg[((size_t)ms * 512 + kc * 128 + dl) * 1024 + obase + o_l];
#pragma unroll
            for (int jb = 0; jb < 8; ++jb)
                acc[jb] += A_l[(bq * 8 + jb) * 128 + dl] * wv;
        }
    }
    int o_g = obase + o_l;
    float bias = (o_g < 512) ? ib[0] : fb[0];
#pragma unroll
    for (int jb = 0; jb < 8; ++jb) {
        int b = bq * 8 + jb;
        float g = acc[jb] + gate_in[b * 1024 + o_g] + bias;
        sg[(b * 8 + ms) * 1024 + o_g] = 1.f / (1.f + expf(-g));
    }
}

// ---------------- K7: mlp x2 + LN2 + gate combine + output. 2 rows per block, 512 threads.
__global__ __launch_bounds__(512) void k_mlp_out(const float* __restrict__ mem1,
                                                 const float* __restrict__ Wmlp,
                                                 const float* __restrict__ bmlp,
                                                 const float* __restrict__ g2,
                                                 const float* __restrict__ b2,
                                                 const float* __restrict__ sg,
                                                 const float* __restrict__ memory,
                                                 float* __restrict__ out) {
    int r0 = blockIdx.x * 2, r1 = r0 + 1;    // bms row indices
    int t = threadIdx.x;                     // 0..511
    __shared__ float A0[512], A1[512], B0[512], B1[512];
    __shared__ float rA[512], rB[512];

    A0[t] = mem1[r0 * 512 + t];
    A1[t] = mem1[r1 * 512 + t];
    __syncthreads();

    // mlp layer 1
    float acc0 = bmlp[t], acc1 = acc0;
#pragma unroll 8
    for (int d = 0; d < 512; ++d) {
        float wv = Wmlp[d * 512 + t];
        acc0 += A0[d] * wv;
        acc1 += A1[d] * wv;
    }
    B0[t] = fmaxf(acc0, 0.f); B1[t] = fmaxf(acc1, 0.f);
    __syncthreads();

    // mlp layer 2 (shared weights)
    float q0 = bmlp[t], q1 = q0;
#pragma unroll 8
    for (int d = 0; d < 512; ++d) {
        float wv = Wmlp[d * 512 + t];
        q0 += B0[d] * wv;
        q1 += B1[d] * wv;
    }
    q0 = fmaxf(q0, 0.f); q1 = fmaxf(q1, 0.f);

    float y0 = A0[t] + q0, y1 = A1[t] + q1;
    float2 s1 = block_sum512_2(y0, y1, rA, rB);
    float mu0 = s1.x * (1.f / 512.f), mu1 = s1.y * (1.f / 512.f);
    float e0 = y0 - mu0, e1 = y1 - mu1;
    float2 s2 = block_sum512_2(e0 * e0, e1 * e1, rA, rB);
    float rstd0 = rsqrtf(s2.x * (1.f / 512.f) + 1e-5f);
    float rstd1 = rsqrtf(s2.y * (1.f / 512.f) + 1e-5f);
    float np0 = e0 * rstd0 * g2[t] + b2[t];
    float np1 = e1 * rstd1 * g2[t] + b2[t];

    float m0 = memory[r0 * 512 + t], m1 = memory[r1 * 512 + t];
    float ig0 = sg[r0 * 1024 + t],       ig1 = sg[r1 * 1024 + t];
    float fg0 = sg[r0 * 1024 + 512 + t], fg1 = sg[r1 * 1024 + 512 + t];
    out[r0 * 512 + t] = ig0 * tanhf(np0) + fg0 * m0;
    out[r1 * 512 + t] = ig1 * tanhf(np1) + fg1 * m1;
}

extern "C" void kernel_launch(void* const* d_in, const int* in_sizes, int n_in,
                              void* d_out, int out_size, void* d_ws, size_t ws_size,
                              hipStream_t stream) {
    const float* inputs = (const float*)d_in[0];
    const float* memory = (const float*)d_in[1];
    const float* Wq  = (const float*)d_in[2];
    const float* bq  = (const float*)d_in[3];
    const float* Wk  = (const float*)d_in[4];
    const float* bk  = (const float*)d_in[5];
    const float* Wv  = (const float*)d_in[6];
    const float* bv  = (const float*)d_in[7];
    const float* Wmlp= (const float*)d_in[8];
    const float* bmlp= (const float*)d_in[9];
    const float* g1  = (const float*)d_in[10];
    const float* b1  = (const float*)d_in[11];
    const float* g2  = (const float*)d_in[12];
    const float* b2  = (const float*)d_in[13];
    const float* Wi  = (const float*)d_in[14];
    const float* bi  = (const float*)d_in[15];
    const float* rw  = (const float*)d_in[16];
    const float* Wr  = (const float*)d_in[17];
    const float* br  = (const float*)d_in[18];
    const float* Wg  = (const float*)d_in[19];
    const float* fb  = (const float*)d_in[20];
    const float* ib  = (const float*)d_in[21];
    float* out = (float*)d_out;

    float* ws = (float*)d_ws;
    float* WikT   = ws + 0;                  // 131072
    float* Wiv    = ws + 131072;             // 131072 (i-major [256][512])
    float* bkf    = ws + 262144;             // 512
    float* bvf    = ws + 262656;             // 512
    float* qbuf   = ws + 263168;             // 262144
    unsigned short* Pb = (unsigned short*)(ws + 525312);    // 64*64*256 bf16 = 524288 floats
    float* cbuf   = ws + 1049600;            // 4096
    float* scores = ws + 1053696;            // 8388608
    float* topkp  = ws + 9442304;            // 12288
    int*   topki  = (int*)(ws + 9454592);    // 12288
    float* giacc  = ws + 9466880;            // 32768
    float* gatein = ws + 9499648;            // 65536
    unsigned short* WiTb = (unsigned short*)(ws + 9565184); // 65536 floats
    float* sgbuf  = ws + 9630720;            // 524288
    float* mem1   = ws + 10155008;           // 262144

    hipMemsetAsync(giacc, 0, (size_t)BB * 512 * sizeof(float), stream);

    k_fuse_w<<<1024, 256, 0, stream>>>(Wi, Wk, Wv, bi, bk, bv, WikT, Wiv, bkf, bvf);
    k_q<<<512, 256, 0, stream>>>(memory, Wq, bq, qbuf);
    k_p<<<4096, 256, 0, stream>>>(qbuf, WikT, bkf, Pb, cbuf);
    k_wiT<<<512, 256, 0, stream>>>(Wi, WiTb);
    k_scores_mfma<<<dim3(32, 64), 256, 0, stream>>>(inputs, Pb, cbuf, scores);
    k_topk<<<4096, 256, 0, stream>>>(scores, topkp, topki);
    k_gimean_mfma<<<dim3(32, 64), 256, 0, stream>>>(inputs, WiTb, bi, rw, giacc);
    k_gatein2<<<256, 256, 0, stream>>>(giacc, Wr, br, gatein);
    k_gates<<<256, 256, 0, stream>>>(memory, Wg, gatein, fb, ib, sgbuf);
    k_att2<<<512, 256, 0, stream>>>(inputs, Wiv, bvf, topkp, topki, memory, g1, b1, mem1);
    k_mlp_out<<<256, 512, 0, stream>>>(mem1, Wmlp, bmlp, g2, b2, sgbuf, memory, out);
}

// Round 4
// 407.461 us; speedup vs baseline: 1.3272x; 1.3272x over previous
//
#include <hip/hip_runtime.h>
#include <hip/hip_bf16.h>
#include <math.h>

// Problem constants
#define BB 64
#define SS 2048
#define IN_ 256
#define MSLOT 8
#define HH 8
#define HD_ 64
#define MM 512
#define NG_ 1024

typedef __attribute__((ext_vector_type(8))) short short8;
typedef __attribute__((ext_vector_type(8))) unsigned short ushort8;
typedef __attribute__((ext_vector_type(4))) unsigned short ushort4v;
typedef __attribute__((ext_vector_type(4))) float f32x4;

__device__ __forceinline__ unsigned short f2bf(float f) {
    unsigned int u = __builtin_bit_cast(unsigned int, f);
    u += 0x7fff + ((u >> 16) & 1);   // round-to-nearest-even
    return (unsigned short)(u >> 16);
}

__device__ __forceinline__ float block_sum256(float v, float* red) {
    int t = threadIdx.x;
    red[t] = v; __syncthreads();
    for (int s = 128; s > 0; s >>= 1) {
        if (t < s) red[t] += red[t + s];
        __syncthreads();
    }
    float r = red[0];
    __syncthreads();
    return r;
}

__device__ __forceinline__ float2 block_sum512_2(float a, float b, float* rA, float* rB) {
    int t = threadIdx.x;
    rA[t] = a; rB[t] = b; __syncthreads();
    for (int s = 256; s > 0; s >>= 1) {
        if (t < s) { rA[t] += rA[t + s]; rB[t] += rB[t + s]; }
        __syncthreads();
    }
    float2 r = make_float2(rA[0], rB[0]);
    __syncthreads();
    return r;
}

// ---- LDS tile staging helpers: 64 rows x 256 cols bf16, 16B-chunk XOR swizzle
__device__ __forceinline__ void stage_tile_bf16(unsigned short* lds,
                                                const unsigned short* __restrict__ src,
                                                int t) {
#pragma unroll
    for (int it = 0; it < 8; ++it) {
        int c = t + it * 256;
        int r = c >> 5, ch = c & 31;
        ushort8 v = *(const ushort8*)(src + (size_t)r * 256 + ch * 8);
        int sch = ch ^ (r & 7);
        *(ushort8*)(lds + r * 256 + sch * 8) = v;
    }
}

__device__ __forceinline__ void stage_tile_f32cvt(unsigned short* lds,
                                                  const float* __restrict__ src,
                                                  int t) {
#pragma unroll
    for (int it = 0; it < 8; ++it) {
        int c = t + it * 256;
        int r = c >> 5, ch = c & 31;
        const float* p = src + (size_t)r * 256 + ch * 8;
        float4 f0 = *(const float4*)p;
        float4 f1 = *(const float4*)(p + 4);
        ushort8 v;
        v[0] = f2bf(f0.x); v[1] = f2bf(f0.y); v[2] = f2bf(f0.z); v[3] = f2bf(f0.w);
        v[4] = f2bf(f1.x); v[5] = f2bf(f1.y); v[6] = f2bf(f1.z); v[7] = f2bf(f1.w);
        int sch = ch ^ (r & 7);
        *(ushort8*)(lds + r * 256 + sch * 8) = v;
    }
}

__device__ __forceinline__ short8 frag_ld(const unsigned short* lds, int row, int chunk) {
    int sch = chunk ^ (row & 7);
    return *(const short8*)(lds + row * 256 + sch * 8);
}

// ---------------- K1a: fused weights. WikT[o][i]=sum_j Wi[i][j]Wk[j][o]; Wiv[i][o]=sum_j Wi[i][j]Wv[j][o]
__global__ __launch_bounds__(256) void k_fuse_w(const float* __restrict__ Wi,
                                                const float* __restrict__ Wk,
                                                const float* __restrict__ Wv,
                                                const float* __restrict__ bi,
                                                const float* __restrict__ bk,
                                                const float* __restrict__ bv,
                                                float* __restrict__ WikT,
                                                float* __restrict__ Wiv,
                                                float* __restrict__ bkf,
                                                float* __restrict__ bvf) {
    int blk = blockIdx.x;          // 0..1023
    int which = blk >> 9;          // 0: k, 1: v
    int o = blk & 511;
    const float* W = which ? Wv : Wk;
    const float* bx = which ? bv : bk;
    float* bf = which ? bvf : bkf;

    __shared__ float col[512];
    __shared__ float red[256];
    int t = threadIdx.x;
    col[t]       = W[t * 512 + o];
    col[t + 256] = W[(t + 256) * 512 + o];
    __syncthreads();

    const float* wi_row = Wi + t * 512;   // t = i (0..255)
    float acc = 0.f;
    for (int j = 0; j < 512; ++j) acc += wi_row[j] * col[j];
    if (which) Wiv[t * 512 + o] = acc;      // i-major
    else       WikT[o * 256 + t] = acc;     // o-major

    float p = bi[t] * col[t] + bi[t + 256] * col[t + 256];
    float s = block_sum256(p, red);
    if (t == 0) bf[o] = s + bx[o];
}

// ---------------- K1b: q[b,ms,o] = memory[b,ms,:]@Wq + bq
__global__ __launch_bounds__(256) void k_q(const float* __restrict__ memory,
                                           const float* __restrict__ Wq,
                                           const float* __restrict__ bq,
                                           float* __restrict__ q) {
    int bms = blockIdx.x;
    __shared__ float row[512];
    int t = threadIdx.x;
    row[t]       = memory[bms * 512 + t];
    row[t + 256] = memory[bms * 512 + t + 256];
    __syncthreads();
    for (int oo = 0; oo < 2; ++oo) {
        int o = oo * 256 + t;
        float acc = bq[o];
        for (int j = 0; j < 512; ++j) acc += row[j] * Wq[j * 512 + o];
        q[bms * 512 + o] = acc;
    }
}

// ---------------- K1c: P[b,hm,i] (bf16); c[b,hm]=sum_d q*bkf
__global__ __launch_bounds__(256) void k_p(const float* __restrict__ q,
                                           const float* __restrict__ WikT,
                                           const float* __restrict__ bkf,
                                           unsigned short* __restrict__ Pb,
                                           float* __restrict__ cbuf) {
    int blk = blockIdx.x;           // b*64 + hm, hm = h*8+ms
    int b = blk >> 6, hm = blk & 63;
    int h = hm >> 3, ms = hm & 7;
    int t = threadIdx.x;
    __shared__ float qv[64];
    __shared__ float red[64];
    if (t < 64) qv[t] = q[(b * 8 + ms) * 512 + h * 64 + t];
    __syncthreads();
    float acc = 0.f;
    for (int d = 0; d < 64; ++d) acc += qv[d] * WikT[(h * 64 + d) * 256 + t];
    Pb[blk * 256 + t] = f2bf(acc);
    if (t < 64) red[t] = qv[t] * bkf[h * 64 + t];
    __syncthreads();
    for (int s = 32; s > 0; s >>= 1) {
        if (t < s) red[t] += red[t + s];
        __syncthreads();
    }
    if (t == 0) cbuf[blk] = red[0];
}

// ---------------- Wi^T -> bf16
__global__ __launch_bounds__(256) void k_wiT(const float* __restrict__ Wi,
                                             unsigned short* __restrict__ WiTb) {
    int d = blockIdx.x;      // 0..511
    int k = threadIdx.x;     // 0..255
    WiTb[d * 256 + k] = f2bf(Wi[k * 512 + d]);
}

// ---------------- tanh(memory) -> bf16, once
__global__ __launch_bounds__(256) void k_tmem(const float* __restrict__ mem,
                                              unsigned short* __restrict__ tm) {
    int i = (blockIdx.x * 256 + threadIdx.x) * 4;   // 256 blocks -> 262144 elems
    float4 v = *(const float4*)(mem + i);
    ushort4v o;
    o[0] = f2bf(tanhf(v.x)); o[1] = f2bf(tanhf(v.y));
    o[2] = f2bf(tanhf(v.z)); o[3] = f2bf(tanhf(v.w));
    *(ushort4v*)(tm + i) = o;
}

// ---------------- K2 (MFMA): scores[b,hm,s] = P[b,hm,:]·inputs[b,s,:] + c[b,hm]
__global__ __launch_bounds__(256) void k_scores_mfma(const float* __restrict__ inputs,
                                                     const unsigned short* __restrict__ Pb,
                                                     const float* __restrict__ cbuf,
                                                     float* __restrict__ scores) {
    __shared__ unsigned short Pl[64 * 256];
    __shared__ unsigned short Il[64 * 256];
    int t = threadIdx.x;
    int stile = blockIdx.x;   // 0..31 (64 s each)
    int b = blockIdx.y;

    stage_tile_bf16(Pl, Pb + (size_t)b * 64 * 256, t);
    const float* src = inputs + ((size_t)b * SS + stile * 64) * IN_;
    stage_tile_f32cvt(Il, src, t);
    __syncthreads();

    int l = t & 63, w = t >> 6;
    int kg = l >> 4, r16 = l & 15;
    short8 a[8];
#pragma unroll
    for (int kk = 0; kk < 8; ++kk) a[kk] = frag_ld(Pl, w * 16 + r16, kk * 4 + kg);

#pragma unroll
    for (int nt = 0; nt < 4; ++nt) {
        f32x4 acc = {0.f, 0.f, 0.f, 0.f};
#pragma unroll
        for (int kk = 0; kk < 8; ++kk) {
            short8 bf = frag_ld(Il, nt * 16 + r16, kk * 4 + kg);
            acc = __builtin_amdgcn_mfma_f32_16x16x32_bf16(a[kk], bf, acc, 0, 0, 0);
        }
        int s = stile * 64 + nt * 16 + r16;
#pragma unroll
        for (int j = 0; j < 4; ++j) {
            int hm = w * 16 + kg * 4 + j;
            scores[((size_t)(b * 64 + hm)) * SS + s] = acc[j] + cbuf[b * 64 + hm];
        }
    }
}

// ---------------- K3: per-row softmax + top-3
__global__ __launch_bounds__(256) void k_topk(const float* __restrict__ scores,
                                              float* __restrict__ topk_p,
                                              int* __restrict__ topk_idx) {
    int row = blockIdx.x;   // b*64 + hm
    const float* sr = scores + (size_t)row * SS;
    int t = threadIdx.x;
    float v[8];
#pragma unroll
    for (int k = 0; k < 8; ++k) v[k] = sr[k * 256 + t];

    __shared__ float red[256];
    __shared__ float vred[256];
    __shared__ int ired[256];

    float m = -INFINITY;
#pragma unroll
    for (int k = 0; k < 8; ++k) m = fmaxf(m, v[k]);
    red[t] = m; __syncthreads();
    for (int s = 128; s > 0; s >>= 1) {
        if (t < s) red[t] = fmaxf(red[t], red[t + s]);
        __syncthreads();
    }
    float rowmax = red[0]; __syncthreads();

    float sum = 0.f;
#pragma unroll
    for (int k = 0; k < 8; ++k) sum += expf(v[k] - rowmax);
    float rowsum = block_sum256(sum, red);

    int found[3]; float fval[3];
    for (int r = 0; r < 3; ++r) {
        float bv = -INFINITY; int bidx = 0x7fffffff;
#pragma unroll
        for (int k = 0; k < 8; ++k) {
            int gi = k * 256 + t;
            bool skip = false;
            for (int j = 0; j < r; ++j) skip = skip || (found[j] == gi);
            float val = skip ? -INFINITY : v[k];
            if (val > bv || (val == bv && gi < bidx)) { bv = val; bidx = gi; }
        }
        vred[t] = bv; ired[t] = bidx; __syncthreads();
        for (int s = 128; s > 0; s >>= 1) {
            if (t < s) {
                float ov = vred[t + s]; int oi = ired[t + s];
                if (ov > vred[t] || (ov == vred[t] && oi < ired[t])) { vred[t] = ov; ired[t] = oi; }
            }
            __syncthreads();
        }
        found[r] = ired[0];
        fval[r] = vred[0];
        __syncthreads();
    }
    if (t == 0) {
#pragma unroll
        for (int r = 0; r < 3; ++r) {
            topk_idx[row * 3 + r] = found[r];
            topk_p[row * 3 + r] = expf(fval[r] - rowmax) / rowsum;
        }
    }
}

// ---------------- K4: gather + att + LN1 fused.
__global__ __launch_bounds__(256) void k_att2(const float* __restrict__ inputs,
                                              const float* __restrict__ Wiv,
                                              const float* __restrict__ bvf,
                                              const float* __restrict__ topk_p,
                                              const int* __restrict__ topk_idx,
                                              const float* __restrict__ memory,
                                              const float* __restrict__ g1,
                                              const float* __restrict__ b1,
                                              float* __restrict__ mem1) {
    int bms = blockIdx.x;           // b*8 + ms
    int b = bms >> 3, ms = bms & 7;
    int t = threadIdx.x;
    __shared__ float w[8 * 256];
    __shared__ float ps[8];
    __shared__ float red[256];

#pragma unroll
    for (int h = 0; h < 8; ++h) {
        int row = (b * 64 + h * 8 + ms) * 3;
        float acc = 0.f, psum = 0.f;
#pragma unroll
        for (int j = 0; j < 3; ++j) {
            int sj = topk_idx[row + j];
            float pj = topk_p[row + j];
            acc += pj * inputs[((size_t)b * SS + sj) * IN_ + t];
            psum += pj;
        }
        w[h * 256 + t] = acc;
        if (t == 0) ps[h] = psum;
    }
    __syncthreads();

    float a_val[2];
#pragma unroll
    for (int oo = 0; oo < 2; ++oo) {
        int o = oo * 256 + t;
        int h = o >> 6;
        float acc = ps[h] * bvf[o];
        const float* wh = w + h * 256;
#pragma unroll 8
        for (int i = 0; i < 256; ++i) acc += wh[i] * Wiv[i * 512 + o];
        a_val[oo] = acc;
    }

    // LN1 on memory + att
    float m0 = memory[bms * 512 + t], m1 = memory[bms * 512 + t + 256];
    float x0 = m0 + a_val[0], x1 = m1 + a_val[1];
    float mu = block_sum256(x0 + x1, red) * (1.f / 512.f);
    float d0 = x0 - mu, d1 = x1 - mu;
    float var = block_sum256(d0 * d0 + d1 * d1, red) * (1.f / 512.f);
    float rstd = rsqrtf(var + 1e-5f);
    mem1[bms * 512 + t]       = d0 * rstd * g1[t] + b1[t];
    mem1[bms * 512 + t + 256] = d1 * rstd * g1[t + 256] + b1[t + 256];
}

// ---------------- K5 (MFMA): giacc[b,d] += sum_s relu(rw[d]*(inputs[b,s,:]@Wi[:,d] + bi[d]))
__global__ __launch_bounds__(256) void k_gimean_mfma(const float* __restrict__ inputs,
                                                     const unsigned short* __restrict__ WiTb,
                                                     const float* __restrict__ bi,
                                                     const float* __restrict__ rw,
                                                     float* __restrict__ giacc) {
    __shared__ unsigned short Al[64 * 256];
    __shared__ unsigned short Bl[64 * 256];
    __shared__ float gl[512];
    int t = threadIdx.x;
    int stile = blockIdx.x;   // 0..31
    int b = blockIdx.y;
    gl[t] = 0.f; gl[t + 256] = 0.f;

    const float* src = inputs + ((size_t)b * SS + stile * 64) * IN_;
    stage_tile_f32cvt(Al, src, t);
    __syncthreads();

    int l = t & 63, w = t >> 6;
    int kg = l >> 4, r16 = l & 15;
    short8 a[8];
#pragma unroll
    for (int kk = 0; kk < 8; ++kk) a[kk] = frag_ld(Al, w * 16 + r16, kk * 4 + kg);

    for (int dt = 0; dt < 8; ++dt) {
        __syncthreads();
        stage_tile_bf16(Bl, WiTb + (size_t)dt * 64 * 256, t);
        __syncthreads();
#pragma unroll
        for (int nt = 0; nt < 4; ++nt) {
            f32x4 acc = {0.f, 0.f, 0.f, 0.f};
#pragma unroll
            for (int kk = 0; kk < 8; ++kk) {
                short8 bf = frag_ld(Bl, nt * 16 + r16, kk * 4 + kg);
                acc = __builtin_amdgcn_mfma_f32_16x16x32_bf16(a[kk], bf, acc, 0, 0, 0);
            }
            int d = dt * 64 + nt * 16 + r16;
            float bid = bi[d], rwd = rw[d];
            float v = 0.f;
#pragma unroll
            for (int j = 0; j < 4; ++j) v += fmaxf(rwd * (acc[j] + bid), 0.f);
            v += __shfl_xor(v, 16);
            v += __shfl_xor(v, 32);
            if (kg == 0) atomicAdd(&gl[d], v);
        }
    }
    __syncthreads();
    atomicAdd(&giacc[b * 512 + t], gl[t]);
    atomicAdd(&giacc[b * 512 + 256 + t], gl[t + 256]);
}

// ---------------- K6a: gate_in[b,o] = (gi_acc[b,:]/S)@Wr + br   (256 blocks)
__global__ __launch_bounds__(256) void k_gatein2(const float* __restrict__ gi_acc,
                                                 const float* __restrict__ Wr,
                                                 const float* __restrict__ br,
                                                 float* __restrict__ gate_in) {
    int b = blockIdx.x >> 2, ot = blockIdx.x & 3;
    int t = threadIdx.x;
    int o = ot * 256 + t;
    __shared__ float gm[512];
    gm[t]       = gi_acc[b * 512 + t] * (1.0f / 2048.0f);
    gm[t + 256] = gi_acc[b * 512 + t + 256] * (1.0f / 2048.0f);
    __syncthreads();
    float acc = br[o];
#pragma unroll 8
    for (int d = 0; d < 512; ++d) acc += gm[d] * Wr[d * 1024 + o];
    gate_in[b * 1024 + o] = acc;
}

// ---------------- K6b (MFMA): sg[b,ms,o] = sigmoid(tanh(mem) @ Wg[ms] + gate_in + bias)
// Per-ms GEMM: M=64 (b), N=1024 (o), K=512. Block = (ms, 64-o tile); K chunks of 128.
__global__ __launch_bounds__(256) void k_gates_mfma(const unsigned short* __restrict__ tmem_b,
                                                    const float* __restrict__ Wg,
                                                    const float* __restrict__ gate_in,
                                                    const float* __restrict__ fb,
                                                    const float* __restrict__ ib,
                                                    float* __restrict__ sg) {
    int ms = blockIdx.x >> 4;
    int otile = blockIdx.x & 15;
    int t = threadIdx.x;
    int l = t & 63, w = t >> 6;
    int kg = l >> 4, r16 = l & 15;
    __shared__ unsigned short Al[64 * 128];      // swizzled [b][k]
    __shared__ unsigned short Bl[64 * 136];      // padded   [o][k]
    f32x4 acc[4];
#pragma unroll
    for (int nt = 0; nt < 4; ++nt) acc[nt] = (f32x4){0.f, 0.f, 0.f, 0.f};

    int o_l = t & 63;
    for (int kc = 0; kc < 4; ++kc) {
        __syncthreads();
        // stage A: tanh-mem rows b=0..63, k = kc*128..+127 (swizzled chunks of 8)
#pragma unroll
        for (int it = 0; it < 4; ++it) {
            int c = t + it * 256;
            int r = c >> 4, ch = c & 15;
            ushort8 v = *(const ushort8*)(tmem_b + (size_t)(r * 8 + ms) * 512 + kc * 128 + ch * 8);
            int sch = ch ^ (r & 7);
            *(ushort8*)(Al + r * 128 + sch * 8) = v;
        }
        // stage B: Wg[ms][kc*128+k][otile*64+o] -> Bl[o][k] (coalesced reads along o)
#pragma unroll
        for (int i = 0; i < 32; ++i) {
            int k_l = (t >> 6) + 4 * i;
            float v = Wg[((size_t)ms * 512 + kc * 128 + k_l) * 1024 + otile * 64 + o_l];
            Bl[o_l * 136 + k_l] = f2bf(v);
        }
        __syncthreads();
#pragma unroll
        for (int kk = 0; kk < 4; ++kk) {
            int ch = kk * 4 + kg;
            short8 a = *(const short8*)(Al + (w * 16 + r16) * 128 + ((ch ^ (r16 & 7)) * 8));
#pragma unroll
            for (int nt = 0; nt < 4; ++nt) {
                short8 bfr = *(const short8*)(Bl + (nt * 16 + r16) * 136 + ch * 8);
                acc[nt] = __builtin_amdgcn_mfma_f32_16x16x32_bf16(a, bfr, acc[nt], 0, 0, 0);
            }
        }
    }
    float ibv = ib[0], fbv = fb[0];
#pragma unroll
    for (int nt = 0; nt < 4; ++nt) {
        int o = otile * 64 + nt * 16 + r16;
        float bias = (o < 512) ? ibv : fbv;
#pragma unroll
        for (int j = 0; j < 4; ++j) {
            int b = w * 16 + kg * 4 + j;
            float g = acc[nt][j] + gate_in[b * 1024 + o] + bias;
            sg[(size_t)(b * 8 + ms) * 1024 + o] = 1.f / (1.f + expf(-g));
        }
    }
}

// ---------------- K7: mlp x2 + LN2 + gate combine + output. 2 rows per block, 512 threads.
__global__ __launch_bounds__(512) void k_mlp_out(const float* __restrict__ mem1,
                                                 const float* __restrict__ Wmlp,
                                                 const float* __restrict__ bmlp,
                                                 const float* __restrict__ g2,
                                                 const float* __restrict__ b2,
                                                 const float* __restrict__ sg,
                                                 const float* __restrict__ memory,
                                                 float* __restrict__ out) {
    int r0 = blockIdx.x * 2, r1 = r0 + 1;    // bms row indices
    int t = threadIdx.x;                     // 0..511
    __shared__ float A0[512], A1[512], B0[512], B1[512];
    __shared__ float rA[512], rB[512];

    A0[t] = mem1[r0 * 512 + t];
    A1[t] = mem1[r1 * 512 + t];
    __syncthreads();

    // mlp layer 1
    float acc0 = bmlp[t], acc1 = acc0;
#pragma unroll 8
    for (int d = 0; d < 512; ++d) {
        float wv = Wmlp[d * 512 + t];
        acc0 += A0[d] * wv;
        acc1 += A1[d] * wv;
    }
    B0[t] = fmaxf(acc0, 0.f); B1[t] = fmaxf(acc1, 0.f);
    __syncthreads();

    // mlp layer 2 (shared weights)
    float q0 = bmlp[t], q1 = q0;
#pragma unroll 8
    for (int d = 0; d < 512; ++d) {
        float wv = Wmlp[d * 512 + t];
        q0 += B0[d] * wv;
        q1 += B1[d] * wv;
    }
    q0 = fmaxf(q0, 0.f); q1 = fmaxf(q1, 0.f);

    float y0 = A0[t] + q0, y1 = A1[t] + q1;
    float2 s1 = block_sum512_2(y0, y1, rA, rB);
    float mu0 = s1.x * (1.f / 512.f), mu1 = s1.y * (1.f / 512.f);
    float e0 = y0 - mu0, e1 = y1 - mu1;
    float2 s2 = block_sum512_2(e0 * e0, e1 * e1, rA, rB);
    float rstd0 = rsqrtf(s2.x * (1.f / 512.f) + 1e-5f);
    float rstd1 = rsqrtf(s2.y * (1.f / 512.f) + 1e-5f);
    float np0 = e0 * rstd0 * g2[t] + b2[t];
    float np1 = e1 * rstd1 * g2[t] + b2[t];

    float m0 = memory[r0 * 512 + t], m1 = memory[r1 * 512 + t];
    float ig0 = sg[r0 * 1024 + t],       ig1 = sg[r1 * 1024 + t];
    float fg0 = sg[r0 * 1024 + 512 + t], fg1 = sg[r1 * 1024 + 512 + t];
    out[r0 * 512 + t] = ig0 * tanhf(np0) + fg0 * m0;
    out[r1 * 512 + t] = ig1 * tanhf(np1) + fg1 * m1;
}

extern "C" void kernel_launch(void* const* d_in, const int* in_sizes, int n_in,
                              void* d_out, int out_size, void* d_ws, size_t ws_size,
                              hipStream_t stream) {
    const float* inputs = (const float*)d_in[0];
    const float* memory = (const float*)d_in[1];
    const float* Wq  = (const float*)d_in[2];
    const float* bq  = (const float*)d_in[3];
    const float* Wk  = (const float*)d_in[4];
    const float* bk  = (const float*)d_in[5];
    const float* Wv  = (const float*)d_in[6];
    const float* bv  = (const float*)d_in[7];
    const float* Wmlp= (const float*)d_in[8];
    const float* bmlp= (const float*)d_in[9];
    const float* g1  = (const float*)d_in[10];
    const float* b1  = (const float*)d_in[11];
    const float* g2  = (const float*)d_in[12];
    const float* b2  = (const float*)d_in[13];
    const float* Wi  = (const float*)d_in[14];
    const float* bi  = (const float*)d_in[15];
    const float* rw  = (const float*)d_in[16];
    const float* Wr  = (const float*)d_in[17];
    const float* br  = (const float*)d_in[18];
    const float* Wg  = (const float*)d_in[19];
    const float* fb  = (const float*)d_in[20];
    const float* ib  = (const float*)d_in[21];
    float* out = (float*)d_out;

    float* ws = (float*)d_ws;
    float* WikT   = ws + 0;                  // 131072
    float* Wiv    = ws + 131072;             // 131072 (i-major [256][512])
    float* bkf    = ws + 262144;             // 512
    float* bvf    = ws + 262656;             // 512
    float* qbuf   = ws + 263168;             // 262144
    unsigned short* Pb = (unsigned short*)(ws + 525312);    // 524288 floats
    float* cbuf   = ws + 1049600;            // 4096
    float* scores = ws + 1053696;            // 8388608
    float* topkp  = ws + 9442304;            // 12288
    int*   topki  = (int*)(ws + 9454592);    // 12288
    float* giacc  = ws + 9466880;            // 32768
    float* gatein = ws + 9499648;            // 65536
    unsigned short* WiTb = (unsigned short*)(ws + 9565184); // 65536 floats
    float* sgbuf  = ws + 9630720;            // 524288
    float* mem1   = ws + 10155008;           // 262144
    unsigned short* tmem_b = (unsigned short*)(ws + 10417152); // 131072 floats (256K ushort)

    hipMemsetAsync(giacc, 0, (size_t)BB * 512 * sizeof(float), stream);

    k_fuse_w<<<1024, 256, 0, stream>>>(Wi, Wk, Wv, bi, bk, bv, WikT, Wiv, bkf, bvf);
    k_q<<<512, 256, 0, stream>>>(memory, Wq, bq, qbuf);
    k_p<<<4096, 256, 0, stream>>>(qbuf, WikT, bkf, Pb, cbuf);
    k_wiT<<<512, 256, 0, stream>>>(Wi, WiTb);
    k_tmem<<<256, 256, 0, stream>>>(memory, tmem_b);
    k_scores_mfma<<<dim3(32, 64), 256, 0, stream>>>(inputs, Pb, cbuf, scores);
    k_topk<<<4096, 256, 0, stream>>>(scores, topkp, topki);
    k_gimean_mfma<<<dim3(32, 64), 256, 0, stream>>>(inputs, WiTb, bi, rw, giacc);
    k_gatein2<<<256, 256, 0, stream>>>(giacc, Wr, br, gatein);
    k_gates_mfma<<<128, 256, 0, stream>>>(tmem_b, Wg, gatein, fb, ib, sgbuf);
    k_att2<<<512, 256, 0, stream>>>(inputs, Wiv, bvf, topkp, topki, memory, g1, b1, mem1);
    k_mlp_out<<<256, 512, 0, stream>>>(mem1, Wmlp, bmlp, g2, b2, sgbuf, memory, out);
}

// Round 5
// 383.494 us; speedup vs baseline: 1.4101x; 1.0625x over previous
//
#include <hip/hip_runtime.h>
#include <hip/hip_bf16.h>
#include <math.h>

// Problem constants
#define BB 64
#define SS 2048
#define IN_ 256
#define MSLOT 8
#define HH 8
#define HD_ 64
#define MM 512
#define NG_ 1024

typedef __attribute__((ext_vector_type(8))) short short8;
typedef __attribute__((ext_vector_type(8))) unsigned short ushort8;
typedef __attribute__((ext_vector_type(4))) unsigned short ushort4v;
typedef __attribute__((ext_vector_type(4))) float f32x4;

__device__ __forceinline__ unsigned short f2bf(float f) {
    unsigned int u = __builtin_bit_cast(unsigned int, f);
    u += 0x7fff + ((u >> 16) & 1);   // round-to-nearest-even
    return (unsigned short)(u >> 16);
}

__device__ __forceinline__ float block_sum256(float v, float* red) {
    int t = threadIdx.x;
    red[t] = v; __syncthreads();
    for (int s = 128; s > 0; s >>= 1) {
        if (t < s) red[t] += red[t + s];
        __syncthreads();
    }
    float r = red[0];
    __syncthreads();
    return r;
}

__device__ __forceinline__ float2 block_sum512_2(float a, float b, float* rA, float* rB) {
    int t = threadIdx.x;
    rA[t] = a; rB[t] = b; __syncthreads();
    for (int s = 256; s > 0; s >>= 1) {
        if (t < s) { rA[t] += rA[t + s]; rB[t] += rB[t + s]; }
        __syncthreads();
    }
    float2 r = make_float2(rA[0], rB[0]);
    __syncthreads();
    return r;
}

// ---- LDS tile staging: 64 rows x 256 cols bf16, 16B-chunk XOR swizzle
__device__ __forceinline__ void stage_tile_f32cvt(unsigned short* lds,
                                                  const float* __restrict__ src,
                                                  int t) {
#pragma unroll
    for (int it = 0; it < 8; ++it) {
        int c = t + it * 256;
        int r = c >> 5, ch = c & 31;
        const float* p = src + (size_t)r * 256 + ch * 8;
        float4 f0 = *(const float4*)p;
        float4 f1 = *(const float4*)(p + 4);
        ushort8 v;
        v[0] = f2bf(f0.x); v[1] = f2bf(f0.y); v[2] = f2bf(f0.z); v[3] = f2bf(f0.w);
        v[4] = f2bf(f1.x); v[5] = f2bf(f1.y); v[6] = f2bf(f1.z); v[7] = f2bf(f1.w);
        int sch = ch ^ (r & 7);
        *(ushort8*)(lds + r * 256 + sch * 8) = v;
    }
}

__device__ __forceinline__ short8 frag_ld(const unsigned short* lds, int row, int chunk) {
    int sch = chunk ^ (row & 7);
    return *(const short8*)(lds + row * 256 + sch * 8);
}

// ---------------- K1a: fused weights. WikT[o][i]=sum_j Wi[i][j]Wk[j][o]; Wiv[i][o]=sum_j Wi[i][j]Wv[j][o]
__global__ __launch_bounds__(256) void k_fuse_w(const float* __restrict__ Wi,
                                                const float* __restrict__ Wk,
                                                const float* __restrict__ Wv,
                                                const float* __restrict__ bi,
                                                const float* __restrict__ bv,
                                                float* __restrict__ WikT,
                                                float* __restrict__ Wiv,
                                                float* __restrict__ bvf) {
    int blk = blockIdx.x;          // 0..1023
    int which = blk >> 9;          // 0: k, 1: v
    int o = blk & 511;
    const float* W = which ? Wv : Wk;

    __shared__ float col[512];
    __shared__ float red[256];
    int t = threadIdx.x;
    col[t]       = W[t * 512 + o];
    col[t + 256] = W[(t + 256) * 512 + o];
    __syncthreads();

    const float* wi_row = Wi + t * 512;   // t = i (0..255)
    float acc = 0.f;
    for (int j = 0; j < 512; ++j) acc += wi_row[j] * col[j];
    if (which) Wiv[t * 512 + o] = acc;      // i-major
    else       WikT[o * 256 + t] = acc;     // o-major

    if (which) {
        float p = bi[t] * col[t] + bi[t + 256] * col[t + 256];
        float s = block_sum256(p, red);
        if (t == 0) bvf[o] = s + bv[o];
    }
}

// ---------------- K1b: q[b,ms,o] = memory[b,ms,:]@Wq + bq
__global__ __launch_bounds__(256) void k_q(const float* __restrict__ memory,
                                           const float* __restrict__ Wq,
                                           const float* __restrict__ bq,
                                           float* __restrict__ q) {
    int bms = blockIdx.x;
    __shared__ float row[512];
    int t = threadIdx.x;
    row[t]       = memory[bms * 512 + t];
    row[t + 256] = memory[bms * 512 + t + 256];
    __syncthreads();
    for (int oo = 0; oo < 2; ++oo) {
        int o = oo * 256 + t;
        float acc = bq[o];
        for (int j = 0; j < 512; ++j) acc += row[j] * Wq[j * 512 + o];
        q[bms * 512 + o] = acc;
    }
}

// ---------------- K1c: P[b,hm,i] (bf16) = sum_d q[b,ms,h*64+d]*WikT[h*64+d][i]
__global__ __launch_bounds__(256) void k_p(const float* __restrict__ q,
                                           const float* __restrict__ WikT,
                                           unsigned short* __restrict__ Pb) {
    int blk = blockIdx.x;           // b*64 + hm, hm = h*8+ms
    int b = blk >> 6, hm = blk & 63;
    int h = hm >> 3, ms = hm & 7;
    int t = threadIdx.x;
    __shared__ float qv[64];
    if (t < 64) qv[t] = q[(b * 8 + ms) * 512 + h * 64 + t];
    __syncthreads();
    float acc = 0.f;
    for (int d = 0; d < 64; ++d) acc += qv[d] * WikT[(h * 64 + d) * 256 + t];
    Pb[blk * 256 + t] = f2bf(acc);
}

// ---------------- Wi^T -> bf16
__global__ __launch_bounds__(256) void k_wiT(const float* __restrict__ Wi,
                                             unsigned short* __restrict__ WiTb) {
    int d = blockIdx.x;      // 0..511
    int k = threadIdx.x;     // 0..255
    WiTb[d * 256 + k] = f2bf(Wi[k * 512 + d]);
}

// ---------------- tanh(memory) -> bf16, once
__global__ __launch_bounds__(256) void k_tmem(const float* __restrict__ mem,
                                              unsigned short* __restrict__ tm) {
    int i = (blockIdx.x * 256 + threadIdx.x) * 4;
    float4 v = *(const float4*)(mem + i);
    ushort4v o;
    o[0] = f2bf(tanhf(v.x)); o[1] = f2bf(tanhf(v.y));
    o[2] = f2bf(tanhf(v.z)); o[3] = f2bf(tanhf(v.w));
    *(ushort4v*)(tm + i) = o;
}

// ---------------- K2: scores in regs + per-chunk softmax/top3 stats (no scores tensor!)
// Per (b, stile=64 s): chunk stats per row hm: max, sumexp(rel max), top3 (val,idx).
// Note: per-row constant c=q·bkf cancels in softmax/topk -> omitted.
__global__ __launch_bounds__(256) void k_scores_stats(const float* __restrict__ inputs,
                                                      const unsigned short* __restrict__ Pb,
                                                      float4* __restrict__ statA,
                                                      float4* __restrict__ statB) {
    __shared__ unsigned short Il[64 * 256];
    int t = threadIdx.x;
    int stile = blockIdx.x;   // 0..31
    int b = blockIdx.y;
    int l = t & 63, w = t >> 6;
    int kg = l >> 4, r16 = l & 15;

    // A fragments direct from global (L2-resident): wave's 16 hm rows
    short8 a[8];
    const unsigned short* pbase = Pb + ((size_t)(b * 64 + w * 16 + r16)) * 256;
#pragma unroll
    for (int kk = 0; kk < 8; ++kk)
        a[kk] = *(const short8*)(pbase + kk * 32 + kg * 8);

    const float* src = inputs + ((size_t)b * SS + stile * 64) * IN_;
    stage_tile_f32cvt(Il, src, t);
    __syncthreads();

    f32x4 acc[4];
#pragma unroll
    for (int nt = 0; nt < 4; ++nt) acc[nt] = (f32x4){0.f, 0.f, 0.f, 0.f};
#pragma unroll
    for (int kk = 0; kk < 8; ++kk) {
#pragma unroll
        for (int nt = 0; nt < 4; ++nt) {
            short8 bfr = frag_ld(Il, nt * 16 + r16, kk * 4 + kg);
            acc[nt] = __builtin_amdgcn_mfma_f32_16x16x32_bf16(a[kk], bfr, acc[nt], 0, 0, 0);
        }
    }

    int sbase = stile * 64;
#pragma unroll
    for (int j = 0; j < 4; ++j) {
        // row hm = w*16 + kg*4 + j ; values acc[nt][j] at s = sbase + nt*16 + r16
        float m = fmaxf(fmaxf(acc[0][j], acc[1][j]), fmaxf(acc[2][j], acc[3][j]));
#pragma unroll
        for (int off = 1; off <= 8; off <<= 1) m = fmaxf(m, __shfl_xor(m, off));
        float se = 0.f;
#pragma unroll
        for (int nt = 0; nt < 4; ++nt) se += expf(acc[nt][j] - m);
#pragma unroll
        for (int off = 1; off <= 8; off <<= 1) se += __shfl_xor(se, off);

        float fv[3]; int fi[3];
#pragma unroll
        for (int r = 0; r < 3; ++r) {
            float bv = -INFINITY; int bidx = 0x7fffffff;
#pragma unroll
            for (int nt = 0; nt < 4; ++nt) {
                int gi = sbase + nt * 16 + r16;
                bool skip = false;
                for (int jj = 0; jj < r; ++jj) skip = skip || (gi == fi[jj]);
                float val = skip ? -INFINITY : acc[nt][j];
                if (val > bv || (val == bv && gi < bidx)) { bv = val; bidx = gi; }
            }
#pragma unroll
            for (int off = 1; off <= 8; off <<= 1) {
                float ov = __shfl_xor(bv, off); int oi = __shfl_xor(bidx, off);
                if (ov > bv || (ov == bv && oi < bidx)) { bv = ov; bidx = oi; }
            }
            fv[r] = bv; fi[r] = bidx;
        }
        if (r16 == 0) {
            int row = b * 64 + w * 16 + kg * 4 + j;
            statA[row * 32 + stile] = make_float4(m, se, fv[0], fv[1]);
            statB[row * 32 + stile] = make_float4(fv[2], __int_as_float(fi[0]),
                                                  __int_as_float(fi[1]), __int_as_float(fi[2]));
        }
    }
}

// ---------------- K3: merge 32 chunk-stats per row -> topk p/idx. One wave per row.
__global__ __launch_bounds__(256) void k_combine(const float4* __restrict__ statA,
                                                 const float4* __restrict__ statB,
                                                 float* __restrict__ topk_p,
                                                 int* __restrict__ topk_idx) {
    int t = threadIdx.x;
    int row = blockIdx.x * 4 + (t >> 6);
    int l = t & 63;

    float m_c = -INFINITY, s_c = 0.f;
    float v[3] = {-INFINITY, -INFINITY, -INFINITY};
    int  ix[3] = {0x7fffffff, 0x7fffffff, 0x7fffffff};
    if (l < 32) {
        float4 A = statA[row * 32 + l];
        float4 B = statB[row * 32 + l];
        m_c = A.x; s_c = A.y;
        v[0] = A.z; v[1] = A.w; v[2] = B.x;
        ix[0] = __float_as_int(B.y); ix[1] = __float_as_int(B.z); ix[2] = __float_as_int(B.w);
    }
    float M = m_c;
#pragma unroll
    for (int off = 1; off <= 32; off <<= 1) M = fmaxf(M, __shfl_xor(M, off));
    float S = s_c * expf(m_c - M);   // l>=32: 0*exp(-inf)=0
#pragma unroll
    for (int off = 1; off <= 32; off <<= 1) S += __shfl_xor(S, off);

    float fv[3]; int fi[3];
#pragma unroll
    for (int r = 0; r < 3; ++r) {
        float bv = -INFINITY; int bidx = 0x7fffffff;
#pragma unroll
        for (int c = 0; c < 3; ++c) {
            bool skip = false;
            for (int jj = 0; jj < r; ++jj) skip = skip || (ix[c] == fi[jj]);
            float val = skip ? -INFINITY : v[c];
            if (val > bv || (val == bv && ix[c] < bidx)) { bv = val; bidx = ix[c]; }
        }
#pragma unroll
        for (int off = 1; off <= 32; off <<= 1) {
            float ov = __shfl_xor(bv, off); int oi = __shfl_xor(bidx, off);
            if (ov > bv || (ov == bv && oi < bidx)) { bv = ov; bidx = oi; }
        }
        fv[r] = bv; fi[r] = bidx;
    }
    if (l == 0) {
#pragma unroll
        for (int r = 0; r < 3; ++r) {
            topk_p[row * 3 + r] = expf(fv[r] - M) / S;
            topk_idx[row * 3 + r] = fi[r];
        }
    }
}

// ---------------- K4: gather + att + LN1 fused.
__global__ __launch_bounds__(256) void k_att2(const float* __restrict__ inputs,
                                              const float* __restrict__ Wiv,
                                              const float* __restrict__ bvf,
                                              const float* __restrict__ topk_p,
                                              const int* __restrict__ topk_idx,
                                              const float* __restrict__ memory,
                                              const float* __restrict__ g1,
                                              const float* __restrict__ b1,
                                              float* __restrict__ mem1) {
    int bms = blockIdx.x;           // b*8 + ms
    int b = bms >> 3, ms = bms & 7;
    int t = threadIdx.x;
    __shared__ float w[8 * 256];
    __shared__ float ps[8];
    __shared__ float red[256];

#pragma unroll
    for (int h = 0; h < 8; ++h) {
        int row = (b * 64 + h * 8 + ms) * 3;
        float acc = 0.f, psum = 0.f;
#pragma unroll
        for (int j = 0; j < 3; ++j) {
            int sj = topk_idx[row + j];
            float pj = topk_p[row + j];
            acc += pj * inputs[((size_t)b * SS + sj) * IN_ + t];
            psum += pj;
        }
        w[h * 256 + t] = acc;
        if (t == 0) ps[h] = psum;
    }
    __syncthreads();

    float a_val[2];
#pragma unroll
    for (int oo = 0; oo < 2; ++oo) {
        int o = oo * 256 + t;
        int h = o >> 6;
        float acc = ps[h] * bvf[o];
        const float* wh = w + h * 256;
#pragma unroll 8
        for (int i = 0; i < 256; ++i) acc += wh[i] * Wiv[i * 512 + o];
        a_val[oo] = acc;
    }

    float m0 = memory[bms * 512 + t], m1 = memory[bms * 512 + t + 256];
    float x0 = m0 + a_val[0], x1 = m1 + a_val[1];
    float mu = block_sum256(x0 + x1, red) * (1.f / 512.f);
    float d0 = x0 - mu, d1 = x1 - mu;
    float var = block_sum256(d0 * d0 + d1 * d1, red) * (1.f / 512.f);
    float rstd = rsqrtf(var + 1e-5f);
    mem1[bms * 512 + t]       = d0 * rstd * g1[t] + b1[t];
    mem1[bms * 512 + t + 256] = d1 * rstd * g1[t + 256] + b1[t + 256];
}

// ---------------- K5: gimean with register-resident WiT fragments.
// Block: (dt 0..3 = 128 d, sg 0..1 = 1024 s half, b). Wave owns 32 d (2 nt groups).
__global__ __launch_bounds__(256) void k_gimean_reg(const float* __restrict__ inputs,
                                                    const unsigned short* __restrict__ WiTb,
                                                    const float* __restrict__ bi,
                                                    const float* __restrict__ rw,
                                                    float* __restrict__ giaccp) {
    __shared__ unsigned short Il[64 * 256];
    int xb = blockIdx.x;             // 0..7
    int dt = xb >> 1, sg = xb & 1;
    int b = blockIdx.y;
    int t = threadIdx.x;
    int l = t & 63, w = t >> 6;
    int kg = l >> 4, r16 = l & 15;
    int dbase = dt * 128 + w * 32;

    short8 bf[2][8];
    float bi_[2], rw_[2];
#pragma unroll
    for (int nt = 0; nt < 2; ++nt) {
        int d = dbase + nt * 16 + r16;
        bi_[nt] = bi[d]; rw_[nt] = rw[d];
        const unsigned short* wb = WiTb + (size_t)d * 256;
#pragma unroll
        for (int kk = 0; kk < 8; ++kk)
            bf[nt][kk] = *(const short8*)(wb + kk * 32 + kg * 8);
    }

    float racc0 = 0.f, racc1 = 0.f;
    for (int i = 0; i < 16; ++i) {
        int stile = sg * 16 + i;
        __syncthreads();
        stage_tile_f32cvt(Il, inputs + ((size_t)b * SS + stile * 64) * IN_, t);
        __syncthreads();
#pragma unroll
        for (int sq = 0; sq < 4; ++sq) {
            f32x4 acc0 = {0.f, 0.f, 0.f, 0.f};
            f32x4 acc1 = {0.f, 0.f, 0.f, 0.f};
#pragma unroll
            for (int kk = 0; kk < 8; ++kk) {
                short8 a = frag_ld(Il, sq * 16 + r16, kk * 4 + kg);
                acc0 = __builtin_amdgcn_mfma_f32_16x16x32_bf16(a, bf[0][kk], acc0, 0, 0, 0);
                acc1 = __builtin_amdgcn_mfma_f32_16x16x32_bf16(a, bf[1][kk], acc1, 0, 0, 0);
            }
#pragma unroll
            for (int j = 0; j < 4; ++j) {
                racc0 += fmaxf(rw_[0] * (acc0[j] + bi_[0]), 0.f);
                racc1 += fmaxf(rw_[1] * (acc1[j] + bi_[1]), 0.f);
            }
        }
    }
    racc0 += __shfl_xor(racc0, 16); racc0 += __shfl_xor(racc0, 32);
    racc1 += __shfl_xor(racc1, 16); racc1 += __shfl_xor(racc1, 32);
    if (kg == 0) {
        giaccp[(size_t)(sg * 64 + b) * 512 + dbase + r16]      = racc0;
        giaccp[(size_t)(sg * 64 + b) * 512 + dbase + 16 + r16] = racc1;
    }
}

// ---------------- K6a: gate_in[b,o] = (sum(giaccp)/S)@Wr + br
__global__ __launch_bounds__(256) void k_gatein2(const float* __restrict__ giaccp,
                                                 const float* __restrict__ Wr,
                                                 const float* __restrict__ br,
                                                 float* __restrict__ gate_in) {
    int b = blockIdx.x >> 2, ot = blockIdx.x & 3;
    int t = threadIdx.x;
    int o = ot * 256 + t;
    __shared__ float gm[512];
    gm[t]       = (giaccp[(size_t)b * 512 + t] + giaccp[(size_t)(64 + b) * 512 + t]) * (1.0f / 2048.0f);
    gm[t + 256] = (giaccp[(size_t)b * 512 + t + 256] + giaccp[(size_t)(64 + b) * 512 + t + 256]) * (1.0f / 2048.0f);
    __syncthreads();
    float acc = br[o];
#pragma unroll 8
    for (int d = 0; d < 512; ++d) acc += gm[d] * Wr[d * 1024 + o];
    gate_in[b * 1024 + o] = acc;
}

// ---------------- K6b (MFMA): sg[b,ms,o] = sigmoid(tanh(mem) @ Wg[ms] + gate_in + bias)
__global__ __launch_bounds__(256) void k_gates_mfma(const unsigned short* __restrict__ tmem_b,
                                                    const float* __restrict__ Wg,
                                                    const float* __restrict__ gate_in,
                                                    const float* __restrict__ fb,
                                                    const float* __restrict__ ib,
                                                    float* __restrict__ sg) {
    int ms = blockIdx.x >> 4;
    int otile = blockIdx.x & 15;
    int t = threadIdx.x;
    int l = t & 63, w = t >> 6;
    int kg = l >> 4, r16 = l & 15;
    __shared__ unsigned short Al[64 * 128];      // swizzled [b][k]
    __shared__ unsigned short Bl[64 * 136];      // padded   [o][k]
    f32x4 acc[4];
#pragma unroll
    for (int nt = 0; nt < 4; ++nt) acc[nt] = (f32x4){0.f, 0.f, 0.f, 0.f};

    int o_l = t & 63;
    for (int kc = 0; kc < 4; ++kc) {
        __syncthreads();
#pragma unroll
        for (int it = 0; it < 4; ++it) {
            int c = t + it * 256;
            int r = c >> 4, ch = c & 15;
            ushort8 v = *(const ushort8*)(tmem_b + (size_t)(r * 8 + ms) * 512 + kc * 128 + ch * 8);
            int sch = ch ^ (r & 7);
            *(ushort8*)(Al + r * 128 + sch * 8) = v;
        }
#pragma unroll
        for (int i = 0; i < 32; ++i) {
            int k_l = (t >> 6) + 4 * i;
            float v = Wg[((size_t)ms * 512 + kc * 128 + k_l) * 1024 + otile * 64 + o_l];
            Bl[o_l * 136 + k_l] = f2bf(v);
        }
        __syncthreads();
#pragma unroll
        for (int kk = 0; kk < 4; ++kk) {
            int ch = kk * 4 + kg;
            short8 a = *(const short8*)(Al + (w * 16 + r16) * 128 + ((ch ^ (r16 & 7)) * 8));
#pragma unroll
            for (int nt = 0; nt < 4; ++nt) {
                short8 bfr = *(const short8*)(Bl + (nt * 16 + r16) * 136 + ch * 8);
                acc[nt] = __builtin_amdgcn_mfma_f32_16x16x32_bf16(a, bfr, acc[nt], 0, 0, 0);
            }
        }
    }
    float ibv = ib[0], fbv = fb[0];
#pragma unroll
    for (int nt = 0; nt < 4; ++nt) {
        int o = otile * 64 + nt * 16 + r16;
        float bias = (o < 512) ? ibv : fbv;
#pragma unroll
        for (int j = 0; j < 4; ++j) {
            int b = w * 16 + kg * 4 + j;
            float g = acc[nt][j] + gate_in[b * 1024 + o] + bias;
            sg[(size_t)(b * 8 + ms) * 1024 + o] = 1.f / (1.f + expf(-g));
        }
    }
}

// ---------------- K7: mlp x2 + LN2 + gate combine + output.
__global__ __launch_bounds__(512) void k_mlp_out(const float* __restrict__ mem1,
                                                 const float* __restrict__ Wmlp,
                                                 const float* __restrict__ bmlp,
                                                 const float* __restrict__ g2,
                                                 const float* __restrict__ b2,
                                                 const float* __restrict__ sg,
                                                 const float* __restrict__ memory,
                                                 float* __restrict__ out) {
    int r0 = blockIdx.x * 2, r1 = r0 + 1;
    int t = threadIdx.x;
    __shared__ float A0[512], A1[512], B0[512], B1[512];
    __shared__ float rA[512], rB[512];

    A0[t] = mem1[r0 * 512 + t];
    A1[t] = mem1[r1 * 512 + t];
    __syncthreads();

    float acc0 = bmlp[t], acc1 = acc0;
#pragma unroll 8
    for (int d = 0; d < 512; ++d) {
        float wv = Wmlp[d * 512 + t];
        acc0 += A0[d] * wv;
        acc1 += A1[d] * wv;
    }
    B0[t] = fmaxf(acc0, 0.f); B1[t] = fmaxf(acc1, 0.f);
    __syncthreads();

    float q0 = bmlp[t], q1 = q0;
#pragma unroll 8
    for (int d = 0; d < 512; ++d) {
        float wv = Wmlp[d * 512 + t];
        q0 += B0[d] * wv;
        q1 += B1[d] * wv;
    }
    q0 = fmaxf(q0, 0.f); q1 = fmaxf(q1, 0.f);

    float y0 = A0[t] + q0, y1 = A1[t] + q1;
    float2 s1 = block_sum512_2(y0, y1, rA, rB);
    float mu0 = s1.x * (1.f / 512.f), mu1 = s1.y * (1.f / 512.f);
    float e0 = y0 - mu0, e1 = y1 - mu1;
    float2 s2 = block_sum512_2(e0 * e0, e1 * e1, rA, rB);
    float rstd0 = rsqrtf(s2.x * (1.f / 512.f) + 1e-5f);
    float rstd1 = rsqrtf(s2.y * (1.f / 512.f) + 1e-5f);
    float np0 = e0 * rstd0 * g2[t] + b2[t];
    float np1 = e1 * rstd1 * g2[t] + b2[t];

    float m0 = memory[r0 * 512 + t], m1 = memory[r1 * 512 + t];
    float ig0 = sg[r0 * 1024 + t],       ig1 = sg[r1 * 1024 + t];
    float fg0 = sg[r0 * 1024 + 512 + t], fg1 = sg[r1 * 1024 + 512 + t];
    out[r0 * 512 + t] = ig0 * tanhf(np0) + fg0 * m0;
    out[r1 * 512 + t] = ig1 * tanhf(np1) + fg1 * m1;
}

extern "C" void kernel_launch(void* const* d_in, const int* in_sizes, int n_in,
                              void* d_out, int out_size, void* d_ws, size_t ws_size,
                              hipStream_t stream) {
    const float* inputs = (const float*)d_in[0];
    const float* memory = (const float*)d_in[1];
    const float* Wq  = (const float*)d_in[2];
    const float* bq  = (const float*)d_in[3];
    const float* Wk  = (const float*)d_in[4];
    const float* bk  = (const float*)d_in[5];
    const float* Wv  = (const float*)d_in[6];
    const float* bv  = (const float*)d_in[7];
    const float* Wmlp= (const float*)d_in[8];
    const float* bmlp= (const float*)d_in[9];
    const float* g1  = (const float*)d_in[10];
    const float* b1  = (const float*)d_in[11];
    const float* g2  = (const float*)d_in[12];
    const float* b2  = (const float*)d_in[13];
    const float* Wi  = (const float*)d_in[14];
    const float* bi  = (const float*)d_in[15];
    const float* rw  = (const float*)d_in[16];
    const float* Wr  = (const float*)d_in[17];
    const float* br  = (const float*)d_in[18];
    const float* Wg  = (const float*)d_in[19];
    const float* fb  = (const float*)d_in[20];
    const float* ib  = (const float*)d_in[21];
    float* out = (float*)d_out;

    float* ws = (float*)d_ws;
    float* WikT   = ws + 0;                   // 131072
    float* Wiv    = ws + 131072;              // 131072
    float* bvf    = ws + 262144;              // 512 (+pad to 262656)
    float* qbuf   = ws + 263168;              // 262144 -> 525312
    unsigned short* Pb = (unsigned short*)(ws + 525312);   // 524288 floats -> 1049600
    float4* statA = (float4*)(ws + 1049600);  // 524288 floats -> 1573888
    float4* statB = (float4*)(ws + 1573888);  // 524288 floats -> 2098176
    float* topkp  = ws + 2098176;             // 12288 -> 2110464
    int*   topki  = (int*)(ws + 2110464);     // 12288 -> 2122752
    float* giaccp = ws + 2122752;             // 2*64*512 = 65536 -> 2188288
    float* gatein = ws + 2188288;             // 65536 -> 2253824
    unsigned short* WiTb = (unsigned short*)(ws + 2253824); // 65536 floats -> 2319360
    float* sgbuf  = ws + 2319360;             // 524288 -> 2843648
    float* mem1   = ws + 2843648;             // 262144 -> 3105792
    unsigned short* tmem_b = (unsigned short*)(ws + 3105792); // 131072 floats -> 3236864

    (void)bk; (void)ws_size; (void)in_sizes; (void)n_in; (void)out_size;

    k_fuse_w<<<1024, 256, 0, stream>>>(Wi, Wk, Wv, bi, bv, WikT, Wiv, bvf);
    k_q<<<512, 256, 0, stream>>>(memory, Wq, bq, qbuf);
    k_p<<<4096, 256, 0, stream>>>(qbuf, WikT, Pb);
    k_wiT<<<512, 256, 0, stream>>>(Wi, WiTb);
    k_tmem<<<256, 256, 0, stream>>>(memory, tmem_b);
    k_scores_stats<<<dim3(32, 64), 256, 0, stream>>>(inputs, Pb, statA, statB);
    k_combine<<<1024, 256, 0, stream>>>(statA, statB, topkp, topki);
    k_gimean_reg<<<dim3(8, 64), 256, 0, stream>>>(inputs, WiTb, bi, rw, giaccp);
    k_gatein2<<<256, 256, 0, stream>>>(giaccp, Wr, br, gatein);
    k_gates_mfma<<<128, 256, 0, stream>>>(tmem_b, Wg, gatein, fb, ib, sgbuf);
    k_att2<<<512, 256, 0, stream>>>(inputs, Wiv, bvf, topkp, topki, memory, g1, b1, mem1);
    k_mlp_out<<<256, 512, 0, stream>>>(mem1, Wmlp, bmlp, g2, b2, sgbuf, memory, out);
}

// Round 6
// 364.692 us; speedup vs baseline: 1.4828x; 1.0516x over previous
//
#include <hip/hip_runtime.h>
#include <hip/hip_bf16.h>
#include <math.h>

// Problem constants
#define BB 64
#define SS 2048
#define IN_ 256
#define MSLOT 8
#define HH 8
#define HD_ 64
#define MM 512
#define NG_ 1024

typedef __attribute__((ext_vector_type(8))) short short8;
typedef __attribute__((ext_vector_type(8))) unsigned short ushort8;
typedef __attribute__((ext_vector_type(4))) unsigned short ushort4v;
typedef __attribute__((ext_vector_type(4))) float f32x4;

__device__ __forceinline__ unsigned short f2bf(float f) {
    unsigned int u = __builtin_bit_cast(unsigned int, f);
    u += 0x7fff + ((u >> 16) & 1);   // round-to-nearest-even
    return (unsigned short)(u >> 16);
}

__device__ __forceinline__ float block_sum256(float v, float* red) {
    int t = threadIdx.x;
    red[t] = v; __syncthreads();
    for (int s = 128; s > 0; s >>= 1) {
        if (t < s) red[t] += red[t + s];
        __syncthreads();
    }
    float r = red[0];
    __syncthreads();
    return r;
}

__device__ __forceinline__ float2 block_sum512_2(float a, float b, float* rA, float* rB) {
    int t = threadIdx.x;
    rA[t] = a; rB[t] = b; __syncthreads();
    for (int s = 256; s > 0; s >>= 1) {
        if (t < s) { rA[t] += rA[t + s]; rB[t] += rB[t + s]; }
        __syncthreads();
    }
    float2 r = make_float2(rA[0], rB[0]);
    __syncthreads();
    return r;
}

// ---- LDS tile staging: 64 rows x 256 cols bf16, 16B-chunk XOR swizzle
__device__ __forceinline__ void stage_tile_f32cvt(unsigned short* lds,
                                                  const float* __restrict__ src,
                                                  int t) {
#pragma unroll
    for (int it = 0; it < 8; ++it) {
        int c = t + it * 256;
        int r = c >> 5, ch = c & 31;
        const float* p = src + (size_t)r * 256 + ch * 8;
        float4 f0 = *(const float4*)p;
        float4 f1 = *(const float4*)(p + 4);
        ushort8 v;
        v[0] = f2bf(f0.x); v[1] = f2bf(f0.y); v[2] = f2bf(f0.z); v[3] = f2bf(f0.w);
        v[4] = f2bf(f1.x); v[5] = f2bf(f1.y); v[6] = f2bf(f1.z); v[7] = f2bf(f1.w);
        int sch = ch ^ (r & 7);
        *(ushort8*)(lds + r * 256 + sch * 8) = v;
    }
}

__device__ __forceinline__ void stage_tile_bf16g(unsigned short* lds,
                                                 const unsigned short* __restrict__ src,
                                                 int t) {
#pragma unroll
    for (int it = 0; it < 8; ++it) {
        int c = t + it * 256;
        int r = c >> 5, ch = c & 31;
        ushort8 v = *(const ushort8*)(src + (size_t)r * 256 + ch * 8);
        int sch = ch ^ (r & 7);
        *(ushort8*)(lds + r * 256 + sch * 8) = v;
    }
}

__device__ __forceinline__ short8 frag_ld(const unsigned short* lds, int row, int chunk) {
    int sch = chunk ^ (row & 7);
    return *(const short8*)(lds + row * 256 + sch * 8);
}

// ---------------- K1a: fused weights. WikT[o][i]=sum_j Wi[i][j]Wk[j][o]; Wiv[i][o]=sum_j Wi[i][j]Wv[j][o]
__global__ __launch_bounds__(256) void k_fuse_w(const float* __restrict__ Wi,
                                                const float* __restrict__ Wk,
                                                const float* __restrict__ Wv,
                                                const float* __restrict__ bi,
                                                const float* __restrict__ bv,
                                                float* __restrict__ WikT,
                                                float* __restrict__ Wiv,
                                                float* __restrict__ bvf) {
    int blk = blockIdx.x;          // 0..1023
    int which = blk >> 9;          // 0: k, 1: v
    int o = blk & 511;
    const float* W = which ? Wv : Wk;

    __shared__ float col[512];
    __shared__ float red[256];
    int t = threadIdx.x;
    col[t]       = W[t * 512 + o];
    col[t + 256] = W[(t + 256) * 512 + o];
    __syncthreads();

    const float* wi_row = Wi + t * 512;   // t = i (0..255)
    float acc = 0.f;
    for (int j = 0; j < 512; ++j) acc += wi_row[j] * col[j];
    if (which) Wiv[t * 512 + o] = acc;      // i-major
    else       WikT[o * 256 + t] = acc;     // o-major

    if (which) {
        float p = bi[t] * col[t] + bi[t + 256] * col[t + 256];
        float s = block_sum256(p, red);
        if (t == 0) bvf[o] = s + bv[o];
    }
}

// ---------------- K1b: q[b,ms,o] = memory[b,ms,:]@Wq + bq
__global__ __launch_bounds__(256) void k_q(const float* __restrict__ memory,
                                           const float* __restrict__ Wq,
                                           const float* __restrict__ bq,
                                           float* __restrict__ q) {
    int bms = blockIdx.x;
    __shared__ float row[512];
    int t = threadIdx.x;
    row[t]       = memory[bms * 512 + t];
    row[t + 256] = memory[bms * 512 + t + 256];
    __syncthreads();
    for (int oo = 0; oo < 2; ++oo) {
        int o = oo * 256 + t;
        float acc = bq[o];
        for (int j = 0; j < 512; ++j) acc += row[j] * Wq[j * 512 + o];
        q[bms * 512 + o] = acc;
    }
}

// ---------------- K1c: P[b,hm,i] (bf16) = sum_d q[b,ms,h*64+d]*WikT[h*64+d][i]
__global__ __launch_bounds__(256) void k_p(const float* __restrict__ q,
                                           const float* __restrict__ WikT,
                                           unsigned short* __restrict__ Pb) {
    int blk = blockIdx.x;           // b*64 + hm, hm = h*8+ms
    int b = blk >> 6, hm = blk & 63;
    int h = hm >> 3, ms = hm & 7;
    int t = threadIdx.x;
    __shared__ float qv[64];
    if (t < 64) qv[t] = q[(b * 8 + ms) * 512 + h * 64 + t];
    __syncthreads();
    float acc = 0.f;
    for (int d = 0; d < 64; ++d) acc += qv[d] * WikT[(h * 64 + d) * 256 + t];
    Pb[blk * 256 + t] = f2bf(acc);
}

// ---------------- Wi^T -> bf16
__global__ __launch_bounds__(256) void k_wiT(const float* __restrict__ Wi,
                                             unsigned short* __restrict__ WiTb) {
    int d = blockIdx.x;      // 0..511
    int k = threadIdx.x;     // 0..255
    WiTb[d * 256 + k] = f2bf(Wi[k * 512 + d]);
}

// ---------------- tanh(memory) -> bf16, once
__global__ __launch_bounds__(256) void k_tmem(const float* __restrict__ mem,
                                              unsigned short* __restrict__ tm) {
    int i = (blockIdx.x * 256 + threadIdx.x) * 4;
    float4 v = *(const float4*)(mem + i);
    ushort4v o;
    o[0] = f2bf(tanhf(v.x)); o[1] = f2bf(tanhf(v.y));
    o[2] = f2bf(tanhf(v.z)); o[3] = f2bf(tanhf(v.w));
    *(ushort4v*)(tm + i) = o;
}

// ---------------- K2: scores in regs + per-chunk softmax/top3 stats.
// Also (optionally) streams the bf16-converted inputs tile back to global for reuse.
// XCD swizzle: blocks of one b cluster on one XCD (Pb stays L2-resident).
__global__ __launch_bounds__(256) void k_scores_stats(const float* __restrict__ inputs,
                                                      const unsigned short* __restrict__ Pb,
                                                      float4* __restrict__ statA,
                                                      float4* __restrict__ statB,
                                                      unsigned short* __restrict__ inputs_bf16) {
    __shared__ unsigned short Il[64 * 256];
    int t = threadIdx.x;
    int hw = blockIdx.x;                    // 0..2047
    int L = (hw & 7) * 256 + (hw >> 3);     // XCD-chunked logical id
    int b = L >> 5, stile = L & 31;
    int l = t & 63, w = t >> 6;
    int kg = l >> 4, r16 = l & 15;

    // A fragments direct from global (L2-resident): wave's 16 hm rows
    short8 a[8];
    const unsigned short* pbase = Pb + ((size_t)(b * 64 + w * 16 + r16)) * 256;
#pragma unroll
    for (int kk = 0; kk < 8; ++kk)
        a[kk] = *(const short8*)(pbase + kk * 32 + kg * 8);

    const float* src = inputs + ((size_t)b * SS + stile * 64) * IN_;
    unsigned short* dst = inputs_bf16 ? inputs_bf16 + ((size_t)b * SS + stile * 64) * IN_ : nullptr;
#pragma unroll
    for (int it = 0; it < 8; ++it) {
        int c = t + it * 256;
        int r = c >> 5, ch = c & 31;
        const float* p = src + (size_t)r * 256 + ch * 8;
        float4 f0 = *(const float4*)p;
        float4 f1 = *(const float4*)(p + 4);
        ushort8 v;
        v[0] = f2bf(f0.x); v[1] = f2bf(f0.y); v[2] = f2bf(f0.z); v[3] = f2bf(f0.w);
        v[4] = f2bf(f1.x); v[5] = f2bf(f1.y); v[6] = f2bf(f1.z); v[7] = f2bf(f1.w);
        int sch = ch ^ (r & 7);
        *(ushort8*)(Il + r * 256 + sch * 8) = v;
        if (dst) *(ushort8*)(dst + (size_t)r * 256 + ch * 8) = v;
    }
    __syncthreads();

    f32x4 acc[4];
#pragma unroll
    for (int nt = 0; nt < 4; ++nt) acc[nt] = (f32x4){0.f, 0.f, 0.f, 0.f};
#pragma unroll
    for (int kk = 0; kk < 8; ++kk) {
#pragma unroll
        for (int nt = 0; nt < 4; ++nt) {
            short8 bfr = frag_ld(Il, nt * 16 + r16, kk * 4 + kg);
            acc[nt] = __builtin_amdgcn_mfma_f32_16x16x32_bf16(a[kk], bfr, acc[nt], 0, 0, 0);
        }
    }

    int sbase = stile * 64;
#pragma unroll
    for (int j = 0; j < 4; ++j) {
        float m = fmaxf(fmaxf(acc[0][j], acc[1][j]), fmaxf(acc[2][j], acc[3][j]));
#pragma unroll
        for (int off = 1; off <= 8; off <<= 1) m = fmaxf(m, __shfl_xor(m, off));
        float se = 0.f;
#pragma unroll
        for (int nt = 0; nt < 4; ++nt) se += expf(acc[nt][j] - m);
#pragma unroll
        for (int off = 1; off <= 8; off <<= 1) se += __shfl_xor(se, off);

        float fv[3]; int fi[3];
#pragma unroll
        for (int r = 0; r < 3; ++r) {
            float bv = -INFINITY; int bidx = 0x7fffffff;
#pragma unroll
            for (int nt = 0; nt < 4; ++nt) {
                int gi = sbase + nt * 16 + r16;
                bool skip = false;
                for (int jj = 0; jj < r; ++jj) skip = skip || (gi == fi[jj]);
                float val = skip ? -INFINITY : acc[nt][j];
                if (val > bv || (val == bv && gi < bidx)) { bv = val; bidx = gi; }
            }
#pragma unroll
            for (int off = 1; off <= 8; off <<= 1) {
                float ov = __shfl_xor(bv, off); int oi = __shfl_xor(bidx, off);
                if (ov > bv || (ov == bv && oi < bidx)) { bv = ov; bidx = oi; }
            }
            fv[r] = bv; fi[r] = bidx;
        }
        if (r16 == 0) {
            int row = b * 64 + w * 16 + kg * 4 + j;
            statA[row * 32 + stile] = make_float4(m, se, fv[0], fv[1]);
            statB[row * 32 + stile] = make_float4(fv[2], __int_as_float(fi[0]),
                                                  __int_as_float(fi[1]), __int_as_float(fi[2]));
        }
    }
}

// ---------------- K3: merge 32 chunk-stats per row -> topk p/idx. One wave per row.
__global__ __launch_bounds__(256) void k_combine(const float4* __restrict__ statA,
                                                 const float4* __restrict__ statB,
                                                 float* __restrict__ topk_p,
                                                 int* __restrict__ topk_idx) {
    int t = threadIdx.x;
    int row = blockIdx.x * 4 + (t >> 6);
    int l = t & 63;

    float m_c = -INFINITY, s_c = 0.f;
    float v[3] = {-INFINITY, -INFINITY, -INFINITY};
    int  ix[3] = {0x7fffffff, 0x7fffffff, 0x7fffffff};
    if (l < 32) {
        float4 A = statA[row * 32 + l];
        float4 B = statB[row * 32 + l];
        m_c = A.x; s_c = A.y;
        v[0] = A.z; v[1] = A.w; v[2] = B.x;
        ix[0] = __float_as_int(B.y); ix[1] = __float_as_int(B.z); ix[2] = __float_as_int(B.w);
    }
    float M = m_c;
#pragma unroll
    for (int off = 1; off <= 32; off <<= 1) M = fmaxf(M, __shfl_xor(M, off));
    float S = s_c * expf(m_c - M);
#pragma unroll
    for (int off = 1; off <= 32; off <<= 1) S += __shfl_xor(S, off);

    float fv[3]; int fi[3];
#pragma unroll
    for (int r = 0; r < 3; ++r) {
        float bv = -INFINITY; int bidx = 0x7fffffff;
#pragma unroll
        for (int c = 0; c < 3; ++c) {
            bool skip = false;
            for (int jj = 0; jj < r; ++jj) skip = skip || (ix[c] == fi[jj]);
            float val = skip ? -INFINITY : v[c];
            if (val > bv || (val == bv && ix[c] < bidx)) { bv = val; bidx = ix[c]; }
        }
#pragma unroll
        for (int off = 1; off <= 32; off <<= 1) {
            float ov = __shfl_xor(bv, off); int oi = __shfl_xor(bidx, off);
            if (ov > bv || (ov == bv && oi < bidx)) { bv = ov; bidx = oi; }
        }
        fv[r] = bv; fi[r] = bidx;
    }
    if (l == 0) {
#pragma unroll
        for (int r = 0; r < 3; ++r) {
            topk_p[row * 3 + r] = expf(fv[r] - M) / S;
            topk_idx[row * 3 + r] = fi[r];
        }
    }
}

// ---------------- K4: gather + att + LN1 fused.
__global__ __launch_bounds__(256) void k_att2(const float* __restrict__ inputs,
                                              const float* __restrict__ Wiv,
                                              const float* __restrict__ bvf,
                                              const float* __restrict__ topk_p,
                                              const int* __restrict__ topk_idx,
                                              const float* __restrict__ memory,
                                              const float* __restrict__ g1,
                                              const float* __restrict__ b1,
                                              float* __restrict__ mem1) {
    int bms = blockIdx.x;           // b*8 + ms
    int b = bms >> 3, ms = bms & 7;
    int t = threadIdx.x;
    __shared__ float w[8 * 256];
    __shared__ float ps[8];
    __shared__ float red[256];

#pragma unroll
    for (int h = 0; h < 8; ++h) {
        int row = (b * 64 + h * 8 + ms) * 3;
        float acc = 0.f, psum = 0.f;
#pragma unroll
        for (int j = 0; j < 3; ++j) {
            int sj = topk_idx[row + j];
            float pj = topk_p[row + j];
            acc += pj * inputs[((size_t)b * SS + sj) * IN_ + t];
            psum += pj;
        }
        w[h * 256 + t] = acc;
        if (t == 0) ps[h] = psum;
    }
    __syncthreads();

    float a_val[2];
#pragma unroll
    for (int oo = 0; oo < 2; ++oo) {
        int o = oo * 256 + t;
        int h = o >> 6;
        float acc = ps[h] * bvf[o];
        const float* wh = w + h * 256;
#pragma unroll 8
        for (int i = 0; i < 256; ++i) acc += wh[i] * Wiv[i * 512 + o];
        a_val[oo] = acc;
    }

    float m0 = memory[bms * 512 + t], m1 = memory[bms * 512 + t + 256];
    float x0 = m0 + a_val[0], x1 = m1 + a_val[1];
    float mu = block_sum256(x0 + x1, red) * (1.f / 512.f);
    float d0 = x0 - mu, d1 = x1 - mu;
    float var = block_sum256(d0 * d0 + d1 * d1, red) * (1.f / 512.f);
    float rstd = rsqrtf(var + 1e-5f);
    mem1[bms * 512 + t]       = d0 * rstd * g1[t] + b1[t];
    mem1[bms * 512 + t + 256] = d1 * rstd * g1[t + 256] + b1[t + 256];
}

// ---------------- K5: gimean with register-resident WiT fragments.
// XCD swizzle: 8 sibling blocks (4 dt x 2 sg) of one b land on one XCD -> L2 absorbs redundancy.
__global__ __launch_bounds__(256) void k_gimean_reg(const float* __restrict__ inputs,
                                                    const unsigned short* __restrict__ inputs_bf16,
                                                    const unsigned short* __restrict__ WiTb,
                                                    const float* __restrict__ bi,
                                                    const float* __restrict__ rw,
                                                    float* __restrict__ giaccp) {
    __shared__ unsigned short Il[64 * 256];
    int hw = blockIdx.x;                   // 0..511
    int L = (hw & 7) * 64 + (hw >> 3);     // XCD-chunked logical id
    int b = L >> 3, xb = L & 7;
    int dt = xb >> 1, sg = xb & 1;
    int t = threadIdx.x;
    int l = t & 63, w = t >> 6;
    int kg = l >> 4, r16 = l & 15;
    int dbase = dt * 128 + w * 32;

    short8 bf[2][8];
    float bi_[2], rw_[2];
#pragma unroll
    for (int nt = 0; nt < 2; ++nt) {
        int d = dbase + nt * 16 + r16;
        bi_[nt] = bi[d]; rw_[nt] = rw[d];
        const unsigned short* wb = WiTb + (size_t)d * 256;
#pragma unroll
        for (int kk = 0; kk < 8; ++kk)
            bf[nt][kk] = *(const short8*)(wb + kk * 32 + kg * 8);
    }

    float racc0 = 0.f, racc1 = 0.f;
    for (int i = 0; i < 16; ++i) {
        int stile = sg * 16 + i;
        __syncthreads();
        if (inputs_bf16)
            stage_tile_bf16g(Il, inputs_bf16 + ((size_t)b * SS + stile * 64) * IN_, t);
        else
            stage_tile_f32cvt(Il, inputs + ((size_t)b * SS + stile * 64) * IN_, t);
        __syncthreads();
#pragma unroll
        for (int sq = 0; sq < 4; ++sq) {
            f32x4 acc0 = {0.f, 0.f, 0.f, 0.f};
            f32x4 acc1 = {0.f, 0.f, 0.f, 0.f};
#pragma unroll
            for (int kk = 0; kk < 8; ++kk) {
                short8 a = frag_ld(Il, sq * 16 + r16, kk * 4 + kg);
                acc0 = __builtin_amdgcn_mfma_f32_16x16x32_bf16(a, bf[0][kk], acc0, 0, 0, 0);
                acc1 = __builtin_amdgcn_mfma_f32_16x16x32_bf16(a, bf[1][kk], acc1, 0, 0, 0);
            }
#pragma unroll
            for (int j = 0; j < 4; ++j) {
                racc0 += fmaxf(rw_[0] * (acc0[j] + bi_[0]), 0.f);
                racc1 += fmaxf(rw_[1] * (acc1[j] + bi_[1]), 0.f);
            }
        }
    }
    racc0 += __shfl_xor(racc0, 16); racc0 += __shfl_xor(racc0, 32);
    racc1 += __shfl_xor(racc1, 16); racc1 += __shfl_xor(racc1, 32);
    if (kg == 0) {
        giaccp[(size_t)(sg * 64 + b) * 512 + dbase + r16]      = racc0;
        giaccp[(size_t)(sg * 64 + b) * 512 + dbase + 16 + r16] = racc1;
    }
}

// ---------------- K6a: gate_in[b,o] = (sum(giaccp)/S)@Wr + br
__global__ __launch_bounds__(256) void k_gatein2(const float* __restrict__ giaccp,
                                                 const float* __restrict__ Wr,
                                                 const float* __restrict__ br,
                                                 float* __restrict__ gate_in) {
    int b = blockIdx.x >> 2, ot = blockIdx.x & 3;
    int t = threadIdx.x;
    int o = ot * 256 + t;
    __shared__ float gm[512];
    gm[t]       = (giaccp[(size_t)b * 512 + t] + giaccp[(size_t)(64 + b) * 512 + t]) * (1.0f / 2048.0f);
    gm[t + 256] = (giaccp[(size_t)b * 512 + t + 256] + giaccp[(size_t)(64 + b) * 512 + t + 256]) * (1.0f / 2048.0f);
    __syncthreads();
    float acc = br[o];
#pragma unroll 8
    for (int d = 0; d < 512; ++d) acc += gm[d] * Wr[d * 1024 + o];
    gate_in[b * 1024 + o] = acc;
}

// ---------------- K6b (MFMA): sg[b,ms,o] = sigmoid(tanh(mem) @ Wg[ms] + gate_in + bias)
__global__ __launch_bounds__(256) void k_gates_mfma(const unsigned short* __restrict__ tmem_b,
                                                    const float* __restrict__ Wg,
                                                    const float* __restrict__ gate_in,
                                                    const float* __restrict__ fb,
                                                    const float* __restrict__ ib,
                                                    float* __restrict__ sg) {
    int ms = blockIdx.x >> 4;
    int otile = blockIdx.x & 15;
    int t = threadIdx.x;
    int l = t & 63, w = t >> 6;
    int kg = l >> 4, r16 = l & 15;
    __shared__ unsigned short Al[64 * 128];      // swizzled [b][k]
    __shared__ unsigned short Bl[64 * 136];      // padded   [o][k]
    f32x4 acc[4];
#pragma unroll
    for (int nt = 0; nt < 4; ++nt) acc[nt] = (f32x4){0.f, 0.f, 0.f, 0.f};

    int o_l = t & 63;
    for (int kc = 0; kc < 4; ++kc) {
        __syncthreads();
#pragma unroll
        for (int it = 0; it < 4; ++it) {
            int c = t + it * 256;
            int r = c >> 4, ch = c & 15;
            ushort8 v = *(const ushort8*)(tmem_b + (size_t)(r * 8 + ms) * 512 + kc * 128 + ch * 8);
            int sch = ch ^ (r & 7);
            *(ushort8*)(Al + r * 128 + sch * 8) = v;
        }
#pragma unroll
        for (int i = 0; i < 32; ++i) {
            int k_l = (t >> 6) + 4 * i;
            float v = Wg[((size_t)ms * 512 + kc * 128 + k_l) * 1024 + otile * 64 + o_l];
            Bl[o_l * 136 + k_l] = f2bf(v);
        }
        __syncthreads();
#pragma unroll
        for (int kk = 0; kk < 4; ++kk) {
            int ch = kk * 4 + kg;
            short8 a = *(const short8*)(Al + (w * 16 + r16) * 128 + ((ch ^ (r16 & 7)) * 8));
#pragma unroll
            for (int nt = 0; nt < 4; ++nt) {
                short8 bfr = *(const short8*)(Bl + (nt * 16 + r16) * 136 + ch * 8);
                acc[nt] = __builtin_amdgcn_mfma_f32_16x16x32_bf16(a, bfr, acc[nt], 0, 0, 0);
            }
        }
    }
    float ibv = ib[0], fbv = fb[0];
#pragma unroll
    for (int nt = 0; nt < 4; ++nt) {
        int o = otile * 64 + nt * 16 + r16;
        float bias = (o < 512) ? ibv : fbv;
#pragma unroll
        for (int j = 0; j < 4; ++j) {
            int b = w * 16 + kg * 4 + j;
            float g = acc[nt][j] + gate_in[b * 1024 + o] + bias;
            sg[(size_t)(b * 8 + ms) * 1024 + o] = 1.f / (1.f + expf(-g));
        }
    }
}

// ---------------- K7: mlp x2 + LN2 + gate combine + output.
__global__ __launch_bounds__(512) void k_mlp_out(const float* __restrict__ mem1,
                                                 const float* __restrict__ Wmlp,
                                                 const float* __restrict__ bmlp,
                                                 const float* __restrict__ g2,
                                                 const float* __restrict__ b2,
                                                 const float* __restrict__ sg,
                                                 const float* __restrict__ memory,
                                                 float* __restrict__ out) {
    int r0 = blockIdx.x * 2, r1 = r0 + 1;
    int t = threadIdx.x;
    __shared__ float A0[512], A1[512], B0[512], B1[512];
    __shared__ float rA[512], rB[512];

    A0[t] = mem1[r0 * 512 + t];
    A1[t] = mem1[r1 * 512 + t];
    __syncthreads();

    float acc0 = bmlp[t], acc1 = acc0;
#pragma unroll 8
    for (int d = 0; d < 512; ++d) {
        float wv = Wmlp[d * 512 + t];
        acc0 += A0[d] * wv;
        acc1 += A1[d] * wv;
    }
    B0[t] = fmaxf(acc0, 0.f); B1[t] = fmaxf(acc1, 0.f);
    __syncthreads();

    float q0 = bmlp[t], q1 = q0;
#pragma unroll 8
    for (int d = 0; d < 512; ++d) {
        float wv = Wmlp[d * 512 + t];
        q0 += B0[d] * wv;
        q1 += B1[d] * wv;
    }
    q0 = fmaxf(q0, 0.f); q1 = fmaxf(q1, 0.f);

    float y0 = A0[t] + q0, y1 = A1[t] + q1;
    float2 s1 = block_sum512_2(y0, y1, rA, rB);
    float mu0 = s1.x * (1.f / 512.f), mu1 = s1.y * (1.f / 512.f);
    float e0 = y0 - mu0, e1 = y1 - mu1;
    float2 s2 = block_sum512_2(e0 * e0, e1 * e1, rA, rB);
    float rstd0 = rsqrtf(s2.x * (1.f / 512.f) + 1e-5f);
    float rstd1 = rsqrtf(s2.y * (1.f / 512.f) + 1e-5f);
    float np0 = e0 * rstd0 * g2[t] + b2[t];
    float np1 = e1 * rstd1 * g2[t] + b2[t];

    float m0 = memory[r0 * 512 + t], m1 = memory[r1 * 512 + t];
    float ig0 = sg[r0 * 1024 + t],       ig1 = sg[r1 * 1024 + t];
    float fg0 = sg[r0 * 1024 + 512 + t], fg1 = sg[r1 * 1024 + 512 + t];
    out[r0 * 512 + t] = ig0 * tanhf(np0) + fg0 * m0;
    out[r1 * 512 + t] = ig1 * tanhf(np1) + fg1 * m1;
}

extern "C" void kernel_launch(void* const* d_in, const int* in_sizes, int n_in,
                              void* d_out, int out_size, void* d_ws, size_t ws_size,
                              hipStream_t stream) {
    const float* inputs = (const float*)d_in[0];
    const float* memory = (const float*)d_in[1];
    const float* Wq  = (const float*)d_in[2];
    const float* bq  = (const float*)d_in[3];
    const float* Wk  = (const float*)d_in[4];
    const float* bk  = (const float*)d_in[5];
    const float* Wv  = (const float*)d_in[6];
    const float* bv  = (const float*)d_in[7];
    const float* Wmlp= (const float*)d_in[8];
    const float* bmlp= (const float*)d_in[9];
    const float* g1  = (const float*)d_in[10];
    const float* b1  = (const float*)d_in[11];
    const float* g2  = (const float*)d_in[12];
    const float* b2  = (const float*)d_in[13];
    const float* Wi  = (const float*)d_in[14];
    const float* bi  = (const float*)d_in[15];
    const float* rw  = (const float*)d_in[16];
    const float* Wr  = (const float*)d_in[17];
    const float* br  = (const float*)d_in[18];
    const float* Wg  = (const float*)d_in[19];
    const float* fb  = (const float*)d_in[20];
    const float* ib  = (const float*)d_in[21];
    float* out = (float*)d_out;

    float* ws = (float*)d_ws;
    float* WikT   = ws + 0;                   // 131072
    float* Wiv    = ws + 131072;              // 131072
    float* bvf    = ws + 262144;              // 512 (+pad)
    float* qbuf   = ws + 263168;              // 262144 -> 525312
    unsigned short* Pb = (unsigned short*)(ws + 525312);   // 524288 floats -> 1049600
    float4* statA = (float4*)(ws + 1049600);  // 524288 floats -> 1573888
    float4* statB = (float4*)(ws + 1573888);  // 524288 floats -> 2098176
    float* topkp  = ws + 2098176;             // -> 2110464
    int*   topki  = (int*)(ws + 2110464);     // -> 2122752
    float* giaccp = ws + 2122752;             // -> 2188288
    float* gatein = ws + 2188288;             // -> 2253824
    unsigned short* WiTb = (unsigned short*)(ws + 2253824); // -> 2319360
    float* sgbuf  = ws + 2319360;             // -> 2843648
    float* mem1   = ws + 2843648;             // -> 3105792
    unsigned short* tmem_b = (unsigned short*)(ws + 3105792); // -> 3236864

    // Optional bf16 input cache: 64*2048*256 ushort = 16,777,216 floats worth (67 MB)
    const size_t base_floats = 3236864;
    const size_t bf16_floats = (size_t)BB * SS * IN_ / 2;   // 16,777,216
    unsigned short* inputs_bf16 = nullptr;
    if (ws_size >= (base_floats + bf16_floats) * sizeof(float))
        inputs_bf16 = (unsigned short*)(ws + base_floats);

    (void)bk; (void)in_sizes; (void)n_in; (void)out_size;

    k_fuse_w<<<1024, 256, 0, stream>>>(Wi, Wk, Wv, bi, bv, WikT, Wiv, bvf);
    k_q<<<512, 256, 0, stream>>>(memory, Wq, bq, qbuf);
    k_p<<<4096, 256, 0, stream>>>(qbuf, WikT, Pb);
    k_wiT<<<512, 256, 0, stream>>>(Wi, WiTb);
    k_tmem<<<256, 256, 0, stream>>>(memory, tmem_b);
    k_scores_stats<<<2048, 256, 0, stream>>>(inputs, Pb, statA, statB, inputs_bf16);
    k_combine<<<1024, 256, 0, stream>>>(statA, statB, topkp, topki);
    k_gimean_reg<<<512, 256, 0, stream>>>(inputs, inputs_bf16, WiTb, bi, rw, giaccp);
    k_gatein2<<<256, 256, 0, stream>>>(giaccp, Wr, br, gatein);
    k_gates_mfma<<<128, 256, 0, stream>>>(tmem_b, Wg, gatein, fb, ib, sgbuf);
    k_att2<<<512, 256, 0, stream>>>(inputs, Wiv, bvf, topkp, topki, memory, g1, b1, mem1);
    k_mlp_out<<<256, 512, 0, stream>>>(mem1, Wmlp, bmlp, g2, b2, sgbuf, memory, out);
}

// Round 7
// 343.603 us; speedup vs baseline: 1.5738x; 1.0614x over previous
//
#include <hip/hip_runtime.h>
#include <hip/hip_bf16.h>
#include <math.h>

// Problem constants
#define BB 64
#define SS 2048
#define IN_ 256
#define MSLOT 8
#define HH 8
#define HD_ 64
#define MM 512
#define NG_ 1024

typedef __attribute__((ext_vector_type(8))) short short8;
typedef __attribute__((ext_vector_type(8))) unsigned short ushort8;
typedef __attribute__((ext_vector_type(4))) unsigned short ushort4v;
typedef __attribute__((ext_vector_type(4))) float f32x4;
typedef unsigned long long u64;
typedef unsigned int u32;

__device__ __forceinline__ unsigned short f2bf(float f) {
    unsigned int u = __builtin_bit_cast(unsigned int, f);
    u += 0x7fff + ((u >> 16) & 1);   // round-to-nearest-even
    return (unsigned short)(u >> 16);
}

// sortable key: larger value -> larger key; equal value -> smaller idx -> larger key
__device__ __forceinline__ u64 score_key(float v, int idx) {
    u32 x = __float_as_uint(v);
    u32 fk = (x & 0x80000000u) ? ~x : (x | 0x80000000u);
    return ((u64)fk << 32) | (u32)(~(u32)idx);
}
__device__ __forceinline__ float key_val(u64 k) {
    u32 fk = (u32)(k >> 32);
    u32 x = (fk & 0x80000000u) ? (fk & 0x7FFFFFFFu) : ~fk;
    return __uint_as_float(x);
}
__device__ __forceinline__ int key_idx(u64 k) { return (int)(~(u32)k); }

// merge two sorted-desc 3-lists (unique keys) -> top3 into a-list. Branch-free-ish.
__device__ __forceinline__ void merge3(u64& a0, u64& a1, u64& a2, u64 b0, u64 b1, u64 b2) {
    bool t0 = a0 >= b0;
    u64 m0 = t0 ? a0 : b0;
    u64 a0x = t0 ? a1 : a0, a1x = t0 ? a2 : a1;
    u64 b0x = t0 ? b0 : b1, b1x = t0 ? b1 : b2;
    bool t1 = a0x >= b0x;
    u64 m1 = t1 ? a0x : b0x;
    u64 a0y = t1 ? a1x : a0x;
    u64 b0y = t1 ? b0x : b1x;
    bool t2 = a0y >= b0y;
    u64 m2 = t2 ? a0y : b0y;
    a0 = m0; a1 = m1; a2 = m2;
}

__device__ __forceinline__ void merge3_shfl(u64& k0, u64& k1, u64& k2, int off) {
    u64 b0 = __shfl_xor(k0, off);
    u64 b1 = __shfl_xor(k1, off);
    u64 b2 = __shfl_xor(k2, off);
    merge3(k0, k1, k2, b0, b1, b2);
}

__device__ __forceinline__ float block_sum256(float v, float* red) {
    int t = threadIdx.x;
    red[t] = v; __syncthreads();
    for (int s = 128; s > 0; s >>= 1) {
        if (t < s) red[t] += red[t + s];
        __syncthreads();
    }
    float r = red[0];
    __syncthreads();
    return r;
}

__device__ __forceinline__ float2 block_sum512_2(float a, float b, float* rA, float* rB) {
    int t = threadIdx.x;
    rA[t] = a; rB[t] = b; __syncthreads();
    for (int s = 256; s > 0; s >>= 1) {
        if (t < s) { rA[t] += rA[t + s]; rB[t] += rB[t + s]; }
        __syncthreads();
    }
    float2 r = make_float2(rA[0], rB[0]);
    __syncthreads();
    return r;
}

// ---- LDS tile staging: 64 rows x 256 cols bf16, 16B-chunk XOR swizzle
__device__ __forceinline__ void stage_tile_f32cvt(unsigned short* lds,
                                                  const float* __restrict__ src,
                                                  int t) {
#pragma unroll
    for (int it = 0; it < 8; ++it) {
        int c = t + it * 256;
        int r = c >> 5, ch = c & 31;
        const float* p = src + (size_t)r * 256 + ch * 8;
        float4 f0 = *(const float4*)p;
        float4 f1 = *(const float4*)(p + 4);
        ushort8 v;
        v[0] = f2bf(f0.x); v[1] = f2bf(f0.y); v[2] = f2bf(f0.z); v[3] = f2bf(f0.w);
        v[4] = f2bf(f1.x); v[5] = f2bf(f1.y); v[6] = f2bf(f1.z); v[7] = f2bf(f1.w);
        int sch = ch ^ (r & 7);
        *(ushort8*)(lds + r * 256 + sch * 8) = v;
    }
}

__device__ __forceinline__ short8 frag_ld(const unsigned short* lds, int row, int chunk) {
    int sch = chunk ^ (row & 7);
    return *(const short8*)(lds + row * 256 + sch * 8);
}

// ---------------- K1a: fused weights
__global__ __launch_bounds__(256) void k_fuse_w(const float* __restrict__ Wi,
                                                const float* __restrict__ Wk,
                                                const float* __restrict__ Wv,
                                                const float* __restrict__ bi,
                                                const float* __restrict__ bv,
                                                float* __restrict__ WikT,
                                                float* __restrict__ Wiv,
                                                float* __restrict__ bvf) {
    int blk = blockIdx.x;          // 0..1023
    int which = blk >> 9;          // 0: k, 1: v
    int o = blk & 511;
    const float* W = which ? Wv : Wk;

    __shared__ float col[512];
    __shared__ float red[256];
    int t = threadIdx.x;
    col[t]       = W[t * 512 + o];
    col[t + 256] = W[(t + 256) * 512 + o];
    __syncthreads();

    const float* wi_row = Wi + t * 512;   // t = i (0..255)
    float acc = 0.f;
    for (int j = 0; j < 512; ++j) acc += wi_row[j] * col[j];
    if (which) Wiv[t * 512 + o] = acc;      // i-major
    else       WikT[o * 256 + t] = acc;     // o-major

    if (which) {
        float p = bi[t] * col[t] + bi[t + 256] * col[t + 256];
        float s = block_sum256(p, red);
        if (t == 0) bvf[o] = s + bv[o];
    }
}

// ---------------- K1b: q = memory@Wq + bq
__global__ __launch_bounds__(256) void k_q(const float* __restrict__ memory,
                                           const float* __restrict__ Wq,
                                           const float* __restrict__ bq,
                                           float* __restrict__ q) {
    int bms = blockIdx.x;
    __shared__ float row[512];
    int t = threadIdx.x;
    row[t]       = memory[bms * 512 + t];
    row[t + 256] = memory[bms * 512 + t + 256];
    __syncthreads();
    for (int oo = 0; oo < 2; ++oo) {
        int o = oo * 256 + t;
        float acc = bq[o];
        for (int j = 0; j < 512; ++j) acc += row[j] * Wq[j * 512 + o];
        q[bms * 512 + o] = acc;
    }
}

// ---------------- K1c: P[b,hm,i] (bf16)
__global__ __launch_bounds__(256) void k_p(const float* __restrict__ q,
                                           const float* __restrict__ WikT,
                                           unsigned short* __restrict__ Pb) {
    int blk = blockIdx.x;           // b*64 + hm
    int b = blk >> 6, hm = blk & 63;
    int h = hm >> 3, ms = hm & 7;
    int t = threadIdx.x;
    __shared__ float qv[64];
    if (t < 64) qv[t] = q[(b * 8 + ms) * 512 + h * 64 + t];
    __syncthreads();
    float acc = 0.f;
    for (int d = 0; d < 64; ++d) acc += qv[d] * WikT[(h * 64 + d) * 256 + t];
    Pb[blk * 256 + t] = f2bf(acc);
}

// ---------------- Wi^T -> bf16 in MFMA fragment order
// WiTf flat idx = f*4096 + kk*512 + kg*128 + r16*8 + e  (f = d/16)
__global__ __launch_bounds__(256) void k_wiT(const float* __restrict__ Wi,
                                             unsigned short* __restrict__ WiTf) {
    int idx = blockIdx.x * 256 + threadIdx.x;   // grid 512 -> 131072
    int e = idx & 7, r16 = (idx >> 3) & 15, kg = (idx >> 7) & 3;
    int kk = (idx >> 9) & 7, f = idx >> 12;
    int d = f * 16 + r16;
    int k = kk * 32 + kg * 8 + e;
    WiTf[idx] = f2bf(Wi[k * 512 + d]);
}

// ---------------- tanh(memory) -> bf16
__global__ __launch_bounds__(256) void k_tmem(const float* __restrict__ mem,
                                              unsigned short* __restrict__ tm) {
    int i = (blockIdx.x * 256 + threadIdx.x) * 4;
    float4 v = *(const float4*)(mem + i);
    ushort4v o;
    o[0] = f2bf(tanhf(v.x)); o[1] = f2bf(tanhf(v.y));
    o[2] = f2bf(tanhf(v.z)); o[3] = f2bf(tanhf(v.w));
    *(ushort4v*)(tm + i) = o;
}

// ---------------- K_BIG: per (b, 64-s tile): scores MFMA + key-based stats  AND  gimean MFMA.
// inputs read from HBM exactly once. XCD swizzle clusters one b per XCD.
__global__ __launch_bounds__(256) void k_big(const float* __restrict__ inputs,
                                             const unsigned short* __restrict__ Pb,
                                             const unsigned short* __restrict__ WiTf,
                                             const float* __restrict__ bi,
                                             const float* __restrict__ rw,
                                             uint4* __restrict__ statA,
                                             uint4* __restrict__ statB,
                                             float* __restrict__ giaccp) {
    __shared__ unsigned short Il[64 * 256];   // 32 KB; reused as f32 score tile later
    float* Sl = (float*)Il;                   // [64][68]
    int t = threadIdx.x;
    int hw = blockIdx.x;                      // 0..2047
    int L = (hw & 7) * 256 + (hw >> 3);
    int b = L >> 5, stile = L & 31;
    int l = t & 63, w = t >> 6;
    int kg = l >> 4, r16 = l & 15;

    // scores A-frags (P rows, L2-resident)
    short8 a[8];
    {
        const unsigned short* pbase = Pb + ((size_t)(b * 64 + w * 16 + r16)) * 256;
#pragma unroll
        for (int kk = 0; kk < 8; ++kk)
            a[kk] = *(const short8*)(pbase + kk * 32 + kg * 8);
    }

    stage_tile_f32cvt(Il, inputs + ((size_t)b * SS + stile * 64) * IN_, t);
    __syncthreads();

    // ---- scores MFMAs: acc[nt][j] = score(hm = w*16+kg*4+j, s_local = nt*16+r16)
    f32x4 acc[4];
#pragma unroll
    for (int nt = 0; nt < 4; ++nt) acc[nt] = (f32x4){0.f, 0.f, 0.f, 0.f};
#pragma unroll
    for (int kk = 0; kk < 8; ++kk) {
#pragma unroll
        for (int nt = 0; nt < 4; ++nt) {
            short8 bfr = frag_ld(Il, nt * 16 + r16, kk * 4 + kg);
            acc[nt] = __builtin_amdgcn_mfma_f32_16x16x32_bf16(a[kk], bfr, acc[nt], 0, 0, 0);
        }
    }

    // ---- gimean MFMAs: wave owns d in [w*128, w*128+128)
    float racc[4][2];
#pragma unroll
    for (int g = 0; g < 4; ++g) { racc[g][0] = 0.f; racc[g][1] = 0.f; }
#pragma unroll
    for (int g = 0; g < 4; ++g) {
        int f0 = w * 8 + g * 2;
        short8 bf0[8], bf1[8];
#pragma unroll
        for (int kk = 0; kk < 8; ++kk) {
            bf0[kk] = *(const short8*)(WiTf + ((size_t)(f0 * 8 + kk) * 64 + l) * 8);
            bf1[kk] = *(const short8*)(WiTf + ((size_t)((f0 + 1) * 8 + kk) * 64 + l) * 8);
        }
        int d0 = w * 128 + g * 32 + r16, d1 = d0 + 16;
        float bi0 = bi[d0], rw0 = rw[d0], bi1 = bi[d1], rw1 = rw[d1];
#pragma unroll
        for (int sq = 0; sq < 4; ++sq) {
            f32x4 g0 = {0.f, 0.f, 0.f, 0.f};
            f32x4 g1v = {0.f, 0.f, 0.f, 0.f};
#pragma unroll
            for (int kk = 0; kk < 8; ++kk) {
                short8 af = frag_ld(Il, sq * 16 + r16, kk * 4 + kg);
                g0  = __builtin_amdgcn_mfma_f32_16x16x32_bf16(af, bf0[kk], g0, 0, 0, 0);
                g1v = __builtin_amdgcn_mfma_f32_16x16x32_bf16(af, bf1[kk], g1v, 0, 0, 0);
            }
#pragma unroll
            for (int j = 0; j < 4; ++j) {
                racc[g][0] += fmaxf(rw0 * (g0[j] + bi0), 0.f);
                racc[g][1] += fmaxf(rw1 * (g1v[j] + bi1), 0.f);
            }
        }
    }
    // reduce over kg lanes (s-groups) and write partials
#pragma unroll
    for (int g = 0; g < 4; ++g) {
        float r0 = racc[g][0], r1 = racc[g][1];
        r0 += __shfl_xor(r0, 16); r0 += __shfl_xor(r0, 32);
        r1 += __shfl_xor(r1, 16); r1 += __shfl_xor(r1, 32);
        if (kg == 0) {
            int d0 = w * 128 + g * 32 + r16;
            giaccp[((size_t)stile * 64 + b) * 512 + d0]      = r0;
            giaccp[((size_t)stile * 64 + b) * 512 + d0 + 16] = r1;
        }
    }

    __syncthreads();   // done reading Il
    // transpose scores into Sl[64][68]
#pragma unroll
    for (int nt = 0; nt < 4; ++nt)
#pragma unroll
        for (int j = 0; j < 4; ++j)
            Sl[(w * 16 + kg * 4 + j) * 68 + nt * 16 + r16] = acc[nt][j];
    __syncthreads();

    // ---- stats: thread t handles row = t>>2, s-chunk (t&3)*16..+15
    int row = t >> 2, cq = t & 3;
    float v[16];
#pragma unroll
    for (int i = 0; i < 16; ++i) v[i] = Sl[row * 68 + cq * 16 + i];

    u64 k0 = 0, k1 = 0, k2 = 0;
#pragma unroll
    for (int i = 0; i < 16; ++i) {
        u64 key = score_key(v[i], stile * 64 + cq * 16 + i);
        bool g0 = key > k0, g1 = key > k1, g2 = key > k2;
        k2 = g1 ? k1 : (g2 ? key : k2);
        k1 = g0 ? k0 : (g1 ? key : k1);
        k0 = g0 ? key : k0;
    }
    merge3_shfl(k0, k1, k2, 1);
    merge3_shfl(k0, k1, k2, 2);

    float m = key_val(k0);    // chunk max (all 4 lanes agree)
    float se = 0.f;
#pragma unroll
    for (int i = 0; i < 16; ++i) se += expf(v[i] - m);
    se += __shfl_xor(se, 1);
    se += __shfl_xor(se, 2);

    if (cq == 0) {
        int grow = (b * 64 + row) * 32 + stile;
        statA[grow] = make_uint4(__float_as_uint(se), (u32)(k0 >> 32), (u32)k0, (u32)(k1 >> 32));
        statB[grow] = make_uint4((u32)k1, (u32)(k2 >> 32), (u32)k2, 0u);
    }
}

// ---------------- K3: merge 32 chunk-stats per row -> topk p/idx. One wave per row.
__global__ __launch_bounds__(256) void k_combine(const uint4* __restrict__ statA,
                                                 const uint4* __restrict__ statB,
                                                 float* __restrict__ topk_p,
                                                 int* __restrict__ topk_idx) {
    int t = threadIdx.x;
    int row = blockIdx.x * 4 + (t >> 6);
    int l = t & 63;

    float s_c = 0.f, m_c = 0.f;
    u64 k0 = 0, k1 = 0, k2 = 0;
    if (l < 32) {
        uint4 A = statA[row * 32 + l];
        uint4 Bv = statB[row * 32 + l];
        s_c = __uint_as_float(A.x);
        k0 = ((u64)A.y << 32) | A.z;
        k1 = ((u64)A.w << 32) | Bv.x;
        k2 = ((u64)Bv.y << 32) | Bv.z;
        m_c = key_val(k0);
    }
    merge3_shfl(k0, k1, k2, 1);
    merge3_shfl(k0, k1, k2, 2);
    merge3_shfl(k0, k1, k2, 4);
    merge3_shfl(k0, k1, k2, 8);
    merge3_shfl(k0, k1, k2, 16);

    float M = key_val(k0);
    float S = (l < 32) ? s_c * expf(m_c - M) : 0.f;
#pragma unroll
    for (int off = 1; off <= 16; off <<= 1) S += __shfl_xor(S, off);

    if (l == 0) {
        u64 ks[3] = {k0, k1, k2};
#pragma unroll
        for (int r = 0; r < 3; ++r) {
            topk_p[row * 3 + r] = expf(key_val(ks[r]) - M) / S;
            topk_idx[row * 3 + r] = key_idx(ks[r]);
        }
    }
}

// ---------------- K4: gather + att + LN1 fused.
__global__ __launch_bounds__(256) void k_att2(const float* __restrict__ inputs,
                                              const float* __restrict__ Wiv,
                                              const float* __restrict__ bvf,
                                              const float* __restrict__ topk_p,
                                              const int* __restrict__ topk_idx,
                                              const float* __restrict__ memory,
                                              const float* __restrict__ g1,
                                              const float* __restrict__ b1,
                                              float* __restrict__ mem1) {
    int bms = blockIdx.x;           // b*8 + ms
    int b = bms >> 3, ms = bms & 7;
    int t = threadIdx.x;
    __shared__ float w[8 * 256];
    __shared__ float ps[8];
    __shared__ float red[256];

#pragma unroll
    for (int h = 0; h < 8; ++h) {
        int row = (b * 64 + h * 8 + ms) * 3;
        float acc = 0.f, psum = 0.f;
#pragma unroll
        for (int j = 0; j < 3; ++j) {
            int sj = topk_idx[row + j];
            float pj = topk_p[row + j];
            acc += pj * inputs[((size_t)b * SS + sj) * IN_ + t];
            psum += pj;
        }
        w[h * 256 + t] = acc;
        if (t == 0) ps[h] = psum;
    }
    __syncthreads();

    float a_val[2];
#pragma unroll
    for (int oo = 0; oo < 2; ++oo) {
        int o = oo * 256 + t;
        int h = o >> 6;
        float acc = ps[h] * bvf[o];
        const float* wh = w + h * 256;
#pragma unroll 8
        for (int i = 0; i < 256; ++i) acc += wh[i] * Wiv[i * 512 + o];
        a_val[oo] = acc;
    }

    float m0 = memory[bms * 512 + t], m1 = memory[bms * 512 + t + 256];
    float x0 = m0 + a_val[0], x1 = m1 + a_val[1];
    float mu = block_sum256(x0 + x1, red) * (1.f / 512.f);
    float d0 = x0 - mu, d1 = x1 - mu;
    float var = block_sum256(d0 * d0 + d1 * d1, red) * (1.f / 512.f);
    float rstd = rsqrtf(var + 1e-5f);
    mem1[bms * 512 + t]       = d0 * rstd * g1[t] + b1[t];
    mem1[bms * 512 + t + 256] = d1 * rstd * g1[t + 256] + b1[t + 256];
}

// ---------------- K6a: gate_in[b,o] = (sum_st giaccp /S)@Wr + br
__global__ __launch_bounds__(256) void k_gatein2(const float* __restrict__ giaccp,
                                                 const float* __restrict__ Wr,
                                                 const float* __restrict__ br,
                                                 float* __restrict__ gate_in) {
    int b = blockIdx.x >> 2, ot = blockIdx.x & 3;
    int t = threadIdx.x;
    int o = ot * 256 + t;
    __shared__ float gm[512];
    float s0 = 0.f, s1 = 0.f;
    for (int st = 0; st < 32; ++st) {
        s0 += giaccp[((size_t)st * 64 + b) * 512 + t];
        s1 += giaccp[((size_t)st * 64 + b) * 512 + t + 256];
    }
    gm[t]       = s0 * (1.0f / 2048.0f);
    gm[t + 256] = s1 * (1.0f / 2048.0f);
    __syncthreads();
    float acc = br[o];
#pragma unroll 8
    for (int d = 0; d < 512; ++d) acc += gm[d] * Wr[d * 1024 + o];
    gate_in[b * 1024 + o] = acc;
}

// ---------------- K6b (MFMA): sg = sigmoid(tanh(mem) @ Wg[ms] + gate_in + bias)
__global__ __launch_bounds__(256) void k_gates_mfma(const unsigned short* __restrict__ tmem_b,
                                                    const float* __restrict__ Wg,
                                                    const float* __restrict__ gate_in,
                                                    const float* __restrict__ fb,
                                                    const float* __restrict__ ib,
                                                    float* __restrict__ sg) {
    int ms = blockIdx.x >> 4;
    int otile = blockIdx.x & 15;
    int t = threadIdx.x;
    int l = t & 63, w = t >> 6;
    int kg = l >> 4, r16 = l & 15;
    __shared__ unsigned short Al[64 * 128];
    __shared__ unsigned short Bl[64 * 136];
    f32x4 acc[4];
#pragma unroll
    for (int nt = 0; nt < 4; ++nt) acc[nt] = (f32x4){0.f, 0.f, 0.f, 0.f};

    int o_l = t & 63;
    for (int kc = 0; kc < 4; ++kc) {
        __syncthreads();
#pragma unroll
        for (int it = 0; it < 4; ++it) {
            int c = t + it * 256;
            int r = c >> 4, ch = c & 15;
            ushort8 v = *(const ushort8*)(tmem_b + (size_t)(r * 8 + ms) * 512 + kc * 128 + ch * 8);
            int sch = ch ^ (r & 7);
            *(ushort8*)(Al + r * 128 + sch * 8) = v;
        }
#pragma unroll
        for (int i = 0; i < 32; ++i) {
            int k_l = (t >> 6) + 4 * i;
            float v = Wg[((size_t)ms * 512 + kc * 128 + k_l) * 1024 + otile * 64 + o_l];
            Bl[o_l * 136 + k_l] = f2bf(v);
        }
        __syncthreads();
#pragma unroll
        for (int kk = 0; kk < 4; ++kk) {
            int ch = kk * 4 + kg;
            short8 a = *(const short8*)(Al + (w * 16 + r16) * 128 + ((ch ^ (r16 & 7)) * 8));
#pragma unroll
            for (int nt = 0; nt < 4; ++nt) {
                short8 bfr = *(const short8*)(Bl + (nt * 16 + r16) * 136 + ch * 8);
                acc[nt] = __builtin_amdgcn_mfma_f32_16x16x32_bf16(a, bfr, acc[nt], 0, 0, 0);
            }
        }
    }
    float ibv = ib[0], fbv = fb[0];
#pragma unroll
    for (int nt = 0; nt < 4; ++nt) {
        int o = otile * 64 + nt * 16 + r16;
        float bias = (o < 512) ? ibv : fbv;
#pragma unroll
        for (int j = 0; j < 4; ++j) {
            int b = w * 16 + kg * 4 + j;
            float g = acc[nt][j] + gate_in[b * 1024 + o] + bias;
            sg[(size_t)(b * 8 + ms) * 1024 + o] = 1.f / (1.f + expf(-g));
        }
    }
}

// ---------------- K7: mlp x2 + LN2 + gate combine + output.
__global__ __launch_bounds__(512) void k_mlp_out(const float* __restrict__ mem1,
                                                 const float* __restrict__ Wmlp,
                                                 const float* __restrict__ bmlp,
                                                 const float* __restrict__ g2,
                                                 const float* __restrict__ b2,
                                                 const float* __restrict__ sg,
                                                 const float* __restrict__ memory,
                                                 float* __restrict__ out) {
    int r0 = blockIdx.x * 2, r1 = r0 + 1;
    int t = threadIdx.x;
    __shared__ float A0[512], A1[512], B0[512], B1[512];
    __shared__ float rA[512], rB[512];

    A0[t] = mem1[r0 * 512 + t];
    A1[t] = mem1[r1 * 512 + t];
    __syncthreads();

    float acc0 = bmlp[t], acc1 = acc0;
#pragma unroll 8
    for (int d = 0; d < 512; ++d) {
        float wv = Wmlp[d * 512 + t];
        acc0 += A0[d] * wv;
        acc1 += A1[d] * wv;
    }
    B0[t] = fmaxf(acc0, 0.f); B1[t] = fmaxf(acc1, 0.f);
    __syncthreads();

    float q0 = bmlp[t], q1 = q0;
#pragma unroll 8
    for (int d = 0; d < 512; ++d) {
        float wv = Wmlp[d * 512 + t];
        q0 += B0[d] * wv;
        q1 += B1[d] * wv;
    }
    q0 = fmaxf(q0, 0.f); q1 = fmaxf(q1, 0.f);

    float y0 = A0[t] + q0, y1 = A1[t] + q1;
    float2 s1 = block_sum512_2(y0, y1, rA, rB);
    float mu0 = s1.x * (1.f / 512.f), mu1 = s1.y * (1.f / 512.f);
    float e0 = y0 - mu0, e1 = y1 - mu1;
    float2 s2 = block_sum512_2(e0 * e0, e1 * e1, rA, rB);
    float rstd0 = rsqrtf(s2.x * (1.f / 512.f) + 1e-5f);
    float rstd1 = rsqrtf(s2.y * (1.f / 512.f) + 1e-5f);
    float np0 = e0 * rstd0 * g2[t] + b2[t];
    float np1 = e1 * rstd1 * g2[t] + b2[t];

    float m0 = memory[r0 * 512 + t], m1 = memory[r1 * 512 + t];
    float ig0 = sg[r0 * 1024 + t],       ig1 = sg[r1 * 1024 + t];
    float fg0 = sg[r0 * 1024 + 512 + t], fg1 = sg[r1 * 1024 + 512 + t];
    out[r0 * 512 + t] = ig0 * tanhf(np0) + fg0 * m0;
    out[r1 * 512 + t] = ig1 * tanhf(np1) + fg1 * m1;
}

extern "C" void kernel_launch(void* const* d_in, const int* in_sizes, int n_in,
                              void* d_out, int out_size, void* d_ws, size_t ws_size,
                              hipStream_t stream) {
    const float* inputs = (const float*)d_in[0];
    const float* memory = (const float*)d_in[1];
    const float* Wq  = (const float*)d_in[2];
    const float* bq  = (const float*)d_in[3];
    const float* Wk  = (const float*)d_in[4];
    const float* Wv  = (const float*)d_in[6];
    const float* Wmlp= (const float*)d_in[8];
    const float* bmlp= (const float*)d_in[9];
    const float* g1  = (const float*)d_in[10];
    const float* b1  = (const float*)d_in[11];
    const float* g2  = (const float*)d_in[12];
    const float* b2  = (const float*)d_in[13];
    const float* Wi  = (const float*)d_in[14];
    const float* bi  = (const float*)d_in[15];
    const float* rw  = (const float*)d_in[16];
    const float* Wr  = (const float*)d_in[17];
    const float* br  = (const float*)d_in[18];
    const float* Wg  = (const float*)d_in[19];
    const float* fb  = (const float*)d_in[20];
    const float* ib  = (const float*)d_in[21];
    const float* bv  = (const float*)d_in[7];
    float* out = (float*)d_out;

    float* ws = (float*)d_ws;
    float* WikT   = ws + 0;                   // 131072
    float* Wiv    = ws + 131072;              // 131072 -> 262144
    float* bvf    = ws + 262144;              // 512 (pad -> 263168)
    float* qbuf   = ws + 263168;              // 262144 -> 525312
    unsigned short* Pb   = (unsigned short*)(ws + 525312);   // 1,048,576 ushort -> 1049600
    unsigned short* WiTf = (unsigned short*)(ws + 1049600);  // 131,072 ushort -> 1115136
    uint4* statA  = (uint4*)(ws + 1115136);   // 4096*32*16B = 524288 floats -> 1639424
    uint4* statB  = (uint4*)(ws + 1639424);   // -> 2163712
    float* topkp  = ws + 2163712;             // -> 2176000
    int*   topki  = (int*)(ws + 2176000);     // -> 2188288
    float* giaccp = ws + 2188288;             // 32*64*512 = 1048576 -> 3236864
    float* gatein = ws + 3236864;             // -> 3302400
    float* sgbuf  = ws + 3302400;             // -> 3826688
    float* mem1   = ws + 3826688;             // -> 4088832
    unsigned short* tmem_b = (unsigned short*)(ws + 4088832); // -> 4219904

    (void)in_sizes; (void)n_in; (void)out_size; (void)ws_size;

    k_fuse_w<<<1024, 256, 0, stream>>>(Wi, Wk, Wv, bi, bv, WikT, Wiv, bvf);
    k_q<<<512, 256, 0, stream>>>(memory, Wq, bq, qbuf);
    k_p<<<4096, 256, 0, stream>>>(qbuf, WikT, Pb);
    k_wiT<<<512, 256, 0, stream>>>(Wi, WiTf);
    k_big<<<2048, 256, 0, stream>>>(inputs, Pb, WiTf, bi, rw, statA, statB, giaccp);
    k_tmem<<<256, 256, 0, stream>>>(memory, tmem_b);
    k_combine<<<1024, 256, 0, stream>>>(statA, statB, topkp, topki);
    k_gatein2<<<256, 256, 0, stream>>>(giaccp, Wr, br, gatein);
    k_gates_mfma<<<128, 256, 0, stream>>>(tmem_b, Wg, gatein, fb, ib, sgbuf);
    k_att2<<<512, 256, 0, stream>>>(inputs, Wiv, bvf, topkp, topki, memory, g1, b1, mem1);
    k_mlp_out<<<256, 512, 0, stream>>>(mem1, Wmlp, bmlp, g2, b2, sgbuf, memory, out);
}